// Round 4
// baseline (3272.610 us; speedup 1.0000x reference)
//
#include <hip/hip_runtime.h>
#include <hip/hip_bf16.h>
#include <math.h>

// ---------------------------------------------------------------------------
// FairRep forward on MI355X. fp32 throughout (no fp32 MFMA on CDNA4).
// Pipeline (21 dispatches):
//   memset stats
//   U1 = x@W1[:126]         (gemm_plain)
//   U2 = x@Wn[:126]         (gemm_plain)
//   pass1: bn1 stats -> finalize -> bn2 stats -> finalize -> tail(x2) -> cla/argmax
//   pass2: front GEMM(x2, builds out_o/out_c on the fly, +b1) -> bn stats/finalize
//          -> tail(x2) -> latents (KLD/samples/cl/twin) -> dec+BCE -> finalize_out
// ---------------------------------------------------------------------------

#define N_      262144
#define DX_     126

// ---- workspace layout (bytes) ----
static const size_t OFF_STATS = 0;                      // 4096 doubles (32 KB)
static const size_t OFF_PAR   = 32768;                  // 4096 floats (16 KB)
static const size_t OFF_BUFA  = 65536;                  // N*128 f32 (U1 / H1o2)
static const size_t SZ_NH     = (size_t)N_ * 128 * 4;
static const size_t OFF_BUFB  = OFF_BUFA + SZ_NH;       // N*128 f32 (U2 / H1c2)
static const size_t OFF_E1    = OFF_BUFB + SZ_NH;       // N*40
static const size_t OFF_E2    = OFF_E1 + (size_t)N_*40*4;
static const size_t OFF_ZX1   = OFF_E2 + (size_t)N_*40*4;
static const size_t OFF_ZS1   = OFF_ZX1 + (size_t)N_*10*4;
static const size_t OFF_ZX2   = OFF_ZS1 + (size_t)N_*10*4;
static const size_t OFF_ZS2   = OFF_ZX2 + (size_t)N_*10*4;
static const size_t OFF_YP    = OFF_ZS2 + (size_t)N_*10*4;

// ---- stats region (double indices) ----
#define ST_P1BN1   0      // [o: sum 0..127, sumsq 128..255][c: 256..511]
#define ST_P1BN2   512
#define ST_P2BN1   1024
#define ST_P2BN2   1536
#define ST_KLD     2048   // dzx, dzs, dxs1, dxs2
#define ST_CL      2052   // Scl, Scl2, Sxcl, Sx
#define ST_TWIN_CNT 2056  // 4
#define ST_TWIN_S1 2060   // 40
#define ST_TWIN_S2 2100   // 40
#define ST_BCE     2140   // r1x, r1a, r2x, r2a, rs1, rs2

// ---- bn param region (float indices): [A(128) B(128)] per branch ----
#define PP1BN1  0
#define PP1BN2  512
#define PP2BN1  1024
#define PP2BN2  1536

__device__ __forceinline__ float softplus_f(float u) {
    return fmaxf(u, 0.0f) + log1pf(expf(-fabsf(u)));
}
__device__ __forceinline__ float sigmoid_f(float u) {
    return 1.0f / (1.0f + expf(-u));
}

// block=256 reduction of a float into a global double accumulator
__device__ __forceinline__ void bred_atomic(float v, float* red, double* target) {
    int t = threadIdx.x;
    red[t] = v; __syncthreads();
    if (t < 128) red[t] += red[t + 128];
    __syncthreads();
    if (t < 64) {
        float x = red[t] + red[t + 64];
        #pragma unroll
        for (int off = 32; off > 0; off >>= 1) x += __shfl_down(x, off);
        if (t == 0) atomicAdd(target, (double)x);
    }
    __syncthreads();
}

// ===========================================================================
// GEMM: C(N x 128) = A(N x K) @ W(K x 128), row-major, no bias.
// BM=128, BK=32, 256 threads, 8x8 micro-tile.
// ===========================================================================
#define BMg 128
#define BKg 32

__global__ __launch_bounds__(256, 4) void gemm_plain_kernel(
    const float* __restrict__ A, int K, const float* __restrict__ W,
    float* __restrict__ C)
{
    __shared__ __align__(16) float As[BKg][BMg + 4];
    __shared__ __align__(16) float Bs[BKg][128];
    const int row0 = blockIdx.x * BMg;
    const int tid  = threadIdx.x;
    const int tr   = (tid / 16) * 8;
    const int tc   = (tid % 16) * 8;
    float acc[8][8] = {};
    const int nk = (K + BKg - 1) / BKg;
    for (int kc = 0; kc < nk; ++kc) {
        const int k0 = kc * BKg;
        #pragma unroll
        for (int i = 0; i < 16; ++i) {
            int idx = tid + i * 256;
            int m = idx / BKg, k = idx % BKg;
            int gk = k0 + k;
            As[k][m] = (gk < K) ? A[(size_t)(row0 + m) * K + gk] : 0.0f;
        }
        #pragma unroll
        for (int i = 0; i < 16; ++i) {
            int idx = tid + i * 256;
            int k = idx / 128, n = idx % 128;
            int gk = k0 + k;
            Bs[k][n] = (gk < K) ? W[(size_t)gk * 128 + n] : 0.0f;
        }
        __syncthreads();
        #pragma unroll
        for (int k = 0; k < BKg; ++k) {
            float4 a0 = *(const float4*)&As[k][tr];
            float4 a1 = *(const float4*)&As[k][tr + 4];
            float4 b0 = *(const float4*)&Bs[k][tc];
            float4 b1v = *(const float4*)&Bs[k][tc + 4];
            float av[8] = {a0.x, a0.y, a0.z, a0.w, a1.x, a1.y, a1.z, a1.w};
            float bv[8] = {b0.x, b0.y, b0.z, b0.w, b1v.x, b1v.y, b1v.z, b1v.w};
            #pragma unroll
            for (int i = 0; i < 8; ++i)
                #pragma unroll
                for (int j = 0; j < 8; ++j)
                    acc[i][j] = fmaf(av[i], bv[j], acc[i][j]);
        }
        __syncthreads();
    }
    #pragma unroll
    for (int i = 0; i < 8; ++i) {
        float4 s0 = {acc[i][0], acc[i][1], acc[i][2], acc[i][3]};
        float4 s1 = {acc[i][4], acc[i][5], acc[i][6], acc[i][7]};
        size_t base = (size_t)(row0 + tr + i) * 128 + tc;
        *(float4*)&C[base]     = s0;
        *(float4*)&C[base + 4] = s1;
    }
}

// ===========================================================================
// Pass-2 front GEMM: A = relu(U2 + a0*Wn[126] + a1*Wn[127] + yp*Wn[128] + bnb)
// C = A @ W1 + b1.  K=128.  May write in place over U2 (branch c) -> no
// restrict on U2/Cout.
// ===========================================================================
__global__ __launch_bounds__(256, 4) void gemm_front_kernel(
    const float* U2, const float* __restrict__ a,
    const float* __restrict__ ypred, const float* __restrict__ Wn,
    const float* __restrict__ bnb, int conj,
    const float* __restrict__ W1, const float* __restrict__ b1,
    float* Cout)
{
    __shared__ __align__(16) float As[BKg][BMg + 4];
    __shared__ __align__(16) float Bs[BKg][128];
    __shared__ float ra0[BMg], ra1[BMg], ryp[BMg];
    __shared__ float w6s[128], w7s[128], w8s[128], bns[128];
    const int row0 = blockIdx.x * BMg;
    const int tid  = threadIdx.x;
    if (tid < 128) {
        int r = row0 + tid;
        float a0 = a[2 * r], a1 = a[2 * r + 1];
        if (conj) { a0 = 1.0f - a0; a1 = 1.0f - a1; }
        ra0[tid] = a0; ra1[tid] = a1; ryp[tid] = ypred[r];
        w6s[tid] = Wn[126 * 128 + tid];
        w7s[tid] = Wn[127 * 128 + tid];
        w8s[tid] = Wn[128 * 128 + tid];
        bns[tid] = bnb[tid];
    }
    __syncthreads();
    const int tr = (tid / 16) * 8;
    const int tc = (tid % 16) * 8;
    float acc[8][8] = {};
    for (int kc = 0; kc < 4; ++kc) {
        const int k0 = kc * BKg;
        #pragma unroll
        for (int i = 0; i < 16; ++i) {
            int idx = tid + i * 256;
            int m = idx / BKg, k = idx % BKg;
            int gk = k0 + k;
            float u = U2[(size_t)(row0 + m) * 128 + gk];
            float v = u + ra0[m] * w6s[gk] + ra1[m] * w7s[gk]
                        + ryp[m] * w8s[gk] + bns[gk];
            As[k][m] = fmaxf(v, 0.0f);
        }
        #pragma unroll
        for (int i = 0; i < 16; ++i) {
            int idx = tid + i * 256;
            int k = idx / 128, n = idx % 128;
            Bs[k][n] = W1[(size_t)(k0 + k) * 128 + n];
        }
        __syncthreads();
        #pragma unroll
        for (int k = 0; k < BKg; ++k) {
            float4 a0 = *(const float4*)&As[k][tr];
            float4 a1 = *(const float4*)&As[k][tr + 4];
            float4 b0 = *(const float4*)&Bs[k][tc];
            float4 b1v = *(const float4*)&Bs[k][tc + 4];
            float av[8] = {a0.x, a0.y, a0.z, a0.w, a1.x, a1.y, a1.z, a1.w};
            float bv[8] = {b0.x, b0.y, b0.z, b0.w, b1v.x, b1v.y, b1v.z, b1v.w};
            #pragma unroll
            for (int i = 0; i < 8; ++i)
                #pragma unroll
                for (int j = 0; j < 8; ++j)
                    acc[i][j] = fmaf(av[i], bv[j], acc[i][j]);
        }
        __syncthreads();
    }
    float bias[8];
    #pragma unroll
    for (int j = 0; j < 8; ++j) bias[j] = b1[tc + j];
    #pragma unroll
    for (int i = 0; i < 8; ++i) {
        float4 s0 = {acc[i][0] + bias[0], acc[i][1] + bias[1],
                     acc[i][2] + bias[2], acc[i][3] + bias[3]};
        float4 s1 = {acc[i][4] + bias[4], acc[i][5] + bias[5],
                     acc[i][6] + bias[6], acc[i][7] + bias[7]};
        size_t base = (size_t)(row0 + tr + i) * 128 + tc;
        *(float4*)&Cout[base]     = s0;
        *(float4*)&Cout[base + 4] = s1;
    }
}

// ===========================================================================
// Pass-1 BN1 stats: h_o = U1 + a0*w126 + a1*w127 + b1 ; h_c with (1-a).
// grid 256 x 256 threads; thread = (col, half); 512 rows each.
// ===========================================================================
__global__ __launch_bounds__(256) void stats_p1_bn1_kernel(
    const float* __restrict__ U1, const float* __restrict__ a,
    const float* __restrict__ W1, const float* __restrict__ b1,
    double* __restrict__ stat)
{
    const int tid = threadIdx.x;
    const int col = tid & 127, half = tid >> 7;
    const int r0 = blockIdx.x * 1024 + half * 512;
    const float w6 = W1[126 * 128 + col], w7 = W1[127 * 128 + col];
    const float bb = b1[col];
    double dso = 0, dqo = 0, dsc = 0, dqc = 0;
    for (int i0 = 0; i0 < 512; i0 += 64) {
        float so = 0, qo = 0, sc = 0, qc = 0;
        for (int i = i0; i < i0 + 64; ++i) {
            int r = r0 + i;
            float u  = U1[(size_t)r * 128 + col];
            float a0 = a[2 * r], a1 = a[2 * r + 1];
            float ho = u + a0 * w6 + a1 * w7 + bb;
            float hc = u + (1.0f - a0) * w6 + (1.0f - a1) * w7 + bb;
            so += ho; qo += ho * ho; sc += hc; qc += hc * hc;
        }
        dso += so; dqo += qo; dsc += sc; dqc += qc;
    }
    __shared__ double red[4][128];
    if (half == 1) { red[0][col]=dso; red[1][col]=dqo; red[2][col]=dsc; red[3][col]=dqc; }
    __syncthreads();
    if (half == 0) {
        atomicAdd(&stat[col],       dso + red[0][col]);
        atomicAdd(&stat[128 + col], dqo + red[1][col]);
        atomicAdd(&stat[256 + col], dsc + red[2][col]);
        atomicAdd(&stat[384 + col], dqc + red[3][col]);
    }
}

// Pass-1 BN2 stats: r1 = relu(A1*h + B1) for both branches.
__global__ __launch_bounds__(256) void stats_p1_bn2_kernel(
    const float* __restrict__ U1, const float* __restrict__ a,
    const float* __restrict__ W1, const float* __restrict__ b1,
    const float* __restrict__ Pbn1, double* __restrict__ stat)
{
    const int tid = threadIdx.x;
    const int col = tid & 127, half = tid >> 7;
    const int r0 = blockIdx.x * 1024 + half * 512;
    const float w6 = W1[126 * 128 + col], w7 = W1[127 * 128 + col];
    const float bb = b1[col];
    const float A1o = Pbn1[col],       B1o = Pbn1[128 + col];
    const float A1c = Pbn1[256 + col], B1c = Pbn1[384 + col];
    double dso = 0, dqo = 0, dsc = 0, dqc = 0;
    for (int i0 = 0; i0 < 512; i0 += 64) {
        float so = 0, qo = 0, sc = 0, qc = 0;
        for (int i = i0; i < i0 + 64; ++i) {
            int r = r0 + i;
            float u  = U1[(size_t)r * 128 + col];
            float a0 = a[2 * r], a1 = a[2 * r + 1];
            float ho = u + a0 * w6 + a1 * w7 + bb;
            float hc = u + (1.0f - a0) * w6 + (1.0f - a1) * w7 + bb;
            float r1o = fmaxf(fmaf(A1o, ho, B1o), 0.0f);
            float r1c = fmaxf(fmaf(A1c, hc, B1c), 0.0f);
            so += r1o; qo += r1o * r1o; sc += r1c; qc += r1c * r1c;
        }
        dso += so; dqo += qo; dsc += sc; dqc += qc;
    }
    __shared__ double red[4][128];
    if (half == 1) { red[0][col]=dso; red[1][col]=dqo; red[2][col]=dsc; red[3][col]=dqc; }
    __syncthreads();
    if (half == 0) {
        atomicAdd(&stat[col],       dso + red[0][col]);
        atomicAdd(&stat[128 + col], dqo + red[1][col]);
        atomicAdd(&stat[256 + col], dsc + red[2][col]);
        atomicAdd(&stat[384 + col], dqc + red[3][col]);
    }
}

// Pass-2 BN1 stats: thread = (col, branch); 1024 rows each.
__global__ __launch_bounds__(256) void stats_p2_bn1_kernel(
    const float* __restrict__ H1o, const float* __restrict__ H1c,
    double* __restrict__ stat)
{
    const int tid = threadIdx.x;
    const int col = tid & 127, br = tid >> 7;
    const float* H = br ? H1c : H1o;
    const int r0 = blockIdx.x * 1024;
    double ds = 0, dq = 0;
    for (int i0 = 0; i0 < 1024; i0 += 64) {
        float s = 0, q = 0;
        for (int i = i0; i < i0 + 64; ++i) {
            float h = H[(size_t)(r0 + i) * 128 + col];
            s += h; q += h * h;
        }
        ds += s; dq += q;
    }
    atomicAdd(&stat[br * 256 + col], ds);
    atomicAdd(&stat[br * 256 + 128 + col], dq);
}

__global__ __launch_bounds__(256) void stats_p2_bn2_kernel(
    const float* __restrict__ H1o, const float* __restrict__ H1c,
    const float* __restrict__ Pbn1, double* __restrict__ stat)
{
    const int tid = threadIdx.x;
    const int col = tid & 127, br = tid >> 7;
    const float* H = br ? H1c : H1o;
    const float A1 = Pbn1[br * 256 + col], B1 = Pbn1[br * 256 + 128 + col];
    const int r0 = blockIdx.x * 1024;
    double ds = 0, dq = 0;
    for (int i0 = 0; i0 < 1024; i0 += 64) {
        float s = 0, q = 0;
        for (int i = i0; i < i0 + 64; ++i) {
            float h = H[(size_t)(r0 + i) * 128 + col];
            float r1 = fmaxf(fmaf(A1, h, B1), 0.0f);
            s += r1; q += r1 * r1;
        }
        ds += s; dq += q;
    }
    atomicAdd(&stat[br * 256 + col], ds);
    atomicAdd(&stat[br * 256 + 128 + col], dq);
}

// grid 2 (branch), 128 threads: mu/var -> scale A, shift B
__global__ void finalize_bn_kernel(const double* __restrict__ stat,
                                   const float* __restrict__ g,
                                   const float* __restrict__ be,
                                   float* __restrict__ Pout)
{
    const int br = blockIdx.x, j = threadIdx.x;
    double s = stat[br * 256 + j], q = stat[br * 256 + 128 + j];
    double mu = s / (double)N_;
    double var = q / (double)N_ - mu * mu;
    float rstd = (float)rsqrt(var + 1e-5);
    float A = g[j] * rstd;
    float B = be[j] - (float)mu * A;
    Pout[br * 256 + j] = A;
    Pout[br * 256 + 128 + j] = B;
}

// ===========================================================================
// Pass-1 tail: r2 = relu(bn2(relu(bn1(h1)))) ; [mx|lx] = r2@W2[:, {0..9,20..29}]
// + b2 ; z = eps*exp(lx/2)+mx.  64 rows/block, 256 threads.
// ===========================================================================
__global__ __launch_bounds__(256) void tail_p1_kernel(
    const float* __restrict__ U1, const float* __restrict__ a, int conj,
    const float* __restrict__ W1, const float* __restrict__ b1,
    const float* __restrict__ A1p, const float* __restrict__ B1p,
    const float* __restrict__ A2p, const float* __restrict__ B2p,
    const float* __restrict__ W2, const float* __restrict__ b2,
    const float* __restrict__ epsk, float* __restrict__ zout)
{
    __shared__ float As[128][69];
    __shared__ float outs[64][24];
    const int row0 = blockIdx.x * 64;
    const int tid  = threadIdx.x;
    for (int i = tid; i < 64 * 128; i += 256) {
        int r = i >> 7, k = i & 127;
        int gr = row0 + r;
        float a0 = a[2 * gr], a1 = a[2 * gr + 1];
        if (conj) { a0 = 1.0f - a0; a1 = 1.0f - a1; }
        float h = U1[(size_t)gr * 128 + k] + a0 * W1[126 * 128 + k]
                + a1 * W1[127 * 128 + k] + b1[k];
        float r1 = fmaxf(fmaf(A1p[k], h, B1p[k]), 0.0f);
        float r2 = fmaxf(fmaf(A2p[k], r1, B2p[k]), 0.0f);
        As[k][r] = r2;
    }
    __syncthreads();
    const int row = tid & 63;
    const int cg  = tid >> 6;                       // 0..3, 5 cols each
    const int wbase = __builtin_amdgcn_readfirstlane((cg < 2) ? cg * 5 : 10 + cg * 5);
    float acc[5] = {};
    for (int k = 0; k < 128; ++k) {
        float av = As[k][row];
        #pragma unroll
        for (int c = 0; c < 5; ++c)
            acc[c] = fmaf(av, W2[k * 40 + wbase + c], acc[c]);
    }
    #pragma unroll
    for (int c = 0; c < 5; ++c)
        outs[row][cg * 5 + c] = acc[c] + b2[wbase + c];
    __syncthreads();
    if (tid < 128) {
        int r = tid & 63, dg = tid >> 6;            // dg 0..1 -> d = dg*5..+4
        int gr = row0 + r;
        #pragma unroll
        for (int c = 0; c < 5; ++c) {
            int d = dg * 5 + c;
            float mx = outs[r][d], lx = outs[r][10 + d];
            zout[(size_t)gr * 10 + d] =
                epsk[(size_t)gr * 10 + d] * expf(0.5f * lx) + mx;
        }
    }
}

// Pass-2 tail: full 40-col output E = r2@W2 + b2.
__global__ __launch_bounds__(256) void tail_p2_kernel(
    const float* __restrict__ H1,
    const float* __restrict__ A1p, const float* __restrict__ B1p,
    const float* __restrict__ A2p, const float* __restrict__ B2p,
    const float* __restrict__ W2, const float* __restrict__ b2,
    float* __restrict__ E)
{
    __shared__ float As[128][69];
    __shared__ float outs[64][44];
    const int row0 = blockIdx.x * 64;
    const int tid  = threadIdx.x;
    for (int i = tid; i < 64 * 128; i += 256) {
        int r = i >> 7, k = i & 127;
        float h = H1[(size_t)(row0 + r) * 128 + k];
        float r1 = fmaxf(fmaf(A1p[k], h, B1p[k]), 0.0f);
        float r2 = fmaxf(fmaf(A2p[k], r1, B2p[k]), 0.0f);
        As[k][r] = r2;
    }
    __syncthreads();
    const int row = tid & 63;
    const int cg  = tid >> 6;                       // 0..3, 10 cols each
    const int wbase = __builtin_amdgcn_readfirstlane(cg * 10);
    float acc[10] = {};
    for (int k = 0; k < 128; ++k) {
        float av = As[k][row];
        #pragma unroll
        for (int c = 0; c < 10; ++c)
            acc[c] = fmaf(av, W2[k * 40 + wbase + c], acc[c]);
    }
    #pragma unroll
    for (int c = 0; c < 10; ++c)
        outs[row][wbase + c] = acc[c] + b2[wbase + c];
    __syncthreads();
    size_t base = (size_t)row0 * 40;
    for (int i = tid; i < 64 * 40; i += 256)
        E[base + i] = outs[i / 40][i % 40];
}

// ===========================================================================
// cla(zx1)+cla(zx2) argmax -> y_pred (float 0/1)
// ===========================================================================
__global__ __launch_bounds__(256) void cla_argmax_kernel(
    const float* __restrict__ zx1, const float* __restrict__ zx2,
    const float* __restrict__ Wc1, const float* __restrict__ bc1,
    const float* __restrict__ Wc2, const float* __restrict__ bc2,
    float* __restrict__ ypred)
{
    const int r = blockIdx.x * 256 + threadIdx.x;
    float z1[10], z2[10];
    #pragma unroll
    for (int d = 0; d < 10; ++d) {
        z1[d] = zx1[(size_t)r * 10 + d];
        z2[d] = zx2[(size_t)r * 10 + d];
    }
    float lg0 = 2.0f * bc2[0], lg1 = 2.0f * bc2[1];
    #pragma unroll
    for (int j = 0; j < 32; ++j) {
        float s1 = bc1[j], s2 = bc1[j];
        #pragma unroll
        for (int d = 0; d < 10; ++d) {
            float w = Wc1[d * 32 + j];
            s1 += z1[d] * w; s2 += z2[d] * w;
        }
        float s = s1 + s2;
        lg0 += s * Wc2[j * 2 + 0];
        lg1 += s * Wc2[j * 2 + 1];
    }
    ypred[r] = (lg1 > lg0) ? 1.0f : 0.0f;
}

// ===========================================================================
// latents: KLDs, z samples, cl (ce+moments), twin group stats.
// ===========================================================================
__device__ __forceinline__ float sym10(const float* m1, const float* l1,
                                       const float* m2, const float* l2)
{
    float t12 = 0, t21 = 0;
    #pragma unroll
    for (int j = 0; j < 10; ++j) {
        float dl = l1[j] - l2[j];
        float md = m1[j] - m2[j]; md *= md;
        t12 += -dl + expf(dl)  + md * expf(-l2[j]);
        t21 +=  dl + expf(-dl) + md * expf(-l1[j]);
    }
    return 0.025f * ((t12 - 10.0f) + (t21 - 10.0f));  // 0.25*( . )/10
}

__device__ __forceinline__ float ce2_of(const float* z, int yv,
    const float* Wc1, const float* bc1, const float* Wc2, const float* bc2)
{
    float lg0 = bc2[0], lg1 = bc2[1];
    #pragma unroll
    for (int j = 0; j < 32; ++j) {
        float s = bc1[j];
        #pragma unroll
        for (int d = 0; d < 10; ++d) s += z[d] * Wc1[d * 32 + j];
        lg0 += s * Wc2[j * 2 + 0];
        lg1 += s * Wc2[j * 2 + 1];
    }
    float m = fmaxf(lg0, lg1);
    float lse = m + logf(expf(lg0 - m) + expf(lg1 - m));
    float ly = yv ? lg1 : lg0;
    return -(ly - lse);
}

__global__ __launch_bounds__(256) void latents_kernel(
    const float* __restrict__ E1, const float* __restrict__ E2,
    const float* __restrict__ eps,
    const int* __restrict__ y, const float* __restrict__ a,
    const float* __restrict__ Wc1, const float* __restrict__ bc1,
    const float* __restrict__ Wc2, const float* __restrict__ bc2,
    float* __restrict__ zx1, float* __restrict__ zs1,
    float* __restrict__ zx2, float* __restrict__ zs2,
    double* __restrict__ stat)
{
    __shared__ float tw_cnt[4], tw_s1[40], tw_s2[40];
    __shared__ float red[256];
    const int tid = threadIdx.x;
    if (tid < 4) tw_cnt[tid] = 0.0f;
    if (tid < 40) { tw_s1[tid] = 0.0f; tw_s2[tid] = 0.0f; }
    __syncthreads();

    const int r = blockIdx.x * 256 + tid;
    const size_t NS = (size_t)N_ * 10;
    float e1[40], e2[40];
    #pragma unroll
    for (int i = 0; i < 40; ++i) {
        e1[i] = E1[(size_t)r * 40 + i];
        e2[i] = E2[(size_t)r * 40 + i];
    }
    // layout: [mx 0..9 | ms 10..19 | lx 20..29 | ls 30..39]
    float s_dzx  = sym10(e1 + 0,  e1 + 20, e2 + 0,  e2 + 20);
    float s_dzs  = sym10(e1 + 10, e1 + 30, e2 + 10, e2 + 30);
    float s_dxs1 = sym10(e1 + 0,  e1 + 20, e1 + 10, e1 + 30);
    float s_dxs2 = sym10(e2 + 0,  e2 + 20, e2 + 10, e2 + 30);

    float z1[10], z2[10];
    #pragma unroll
    for (int d = 0; d < 10; ++d) {
        size_t rd = (size_t)r * 10 + d;
        float v1 = eps[4 * NS + rd] * expf(0.5f * e1[20 + d]) + e1[d];
        float t1 = eps[5 * NS + rd] * expf(0.5f * e1[30 + d]) + e1[10 + d];
        float v2 = eps[6 * NS + rd] * expf(0.5f * e2[20 + d]) + e2[d];
        float t2 = eps[7 * NS + rd] * expf(0.5f * e2[30 + d]) + e2[10 + d];
        zx1[rd] = v1; zs1[rd] = t1; zx2[rd] = v2; zs2[rd] = t2;
        z1[d] = v1; z2[d] = v2;
    }

    const int yv = y[r];
    float ce1 = ce2_of(z1, yv, Wc1, bc1, Wc2, bc2);
    float ce2 = ce2_of(z2, yv, Wc1, bc1, Wc2, bc2);
    float cl = 0.5f * (ce1 + ce2);
    float atag = (a[2 * r + 1] > a[2 * r]) ? 1.0f : 0.0f;

    // twin group stats on z1
    int gid = yv * 2 + (int)atag;
    atomicAdd(&tw_cnt[gid], 1.0f);
    #pragma unroll
    for (int d = 0; d < 10; ++d) {
        atomicAdd(&tw_s1[gid * 10 + d], z1[d]);
        atomicAdd(&tw_s2[gid * 10 + d], z1[d] * z1[d]);
    }

    bred_atomic(s_dzx,  red, &stat[ST_KLD + 0]);
    bred_atomic(s_dzs,  red, &stat[ST_KLD + 1]);
    bred_atomic(s_dxs1, red, &stat[ST_KLD + 2]);
    bred_atomic(s_dxs2, red, &stat[ST_KLD + 3]);
    bred_atomic(cl,        red, &stat[ST_CL + 0]);
    bred_atomic(cl * cl,   red, &stat[ST_CL + 1]);
    bred_atomic(atag * cl, red, &stat[ST_CL + 2]);
    bred_atomic(atag,      red, &stat[ST_CL + 3]);

    if (tid < 4)  atomicAdd(&stat[ST_TWIN_CNT + tid], (double)tw_cnt[tid]);
    if (tid < 40) {
        atomicAdd(&stat[ST_TWIN_S1 + tid], (double)tw_s1[tid]);
        atomicAdd(&stat[ST_TWIN_S2 + tid], (double)tw_s2[tid]);
    }
}

// ===========================================================================
// Decoder + BCE sums for the 4 combos.
// ===========================================================================
__global__ __launch_bounds__(256) void dec_bce_kernel(
    const float* __restrict__ zx1, const float* __restrict__ zs1,
    const float* __restrict__ zx2, const float* __restrict__ zs2,
    const float* __restrict__ x, const float* __restrict__ a,
    const float* __restrict__ Wd1, const float* __restrict__ bd1,
    const float* __restrict__ Wd2, const float* __restrict__ bd2,
    double* __restrict__ stat)
{
    const int r = blockIdx.x * 256 + threadIdx.x;
    float v1[10], v2[10], v3[10], v4[10];
    #pragma unroll
    for (int d = 0; d < 10; ++d) {
        size_t rd = (size_t)r * 10 + d;
        v1[d] = zx1[rd]; v2[d] = zs1[rd]; v3[d] = zx2[rd]; v4[d] = zs2[rd];
    }
    float hr1[16], hr2[16], hs1[16], hs2[16];
    #pragma unroll
    for (int j = 0; j < 16; ++j) {
        float s11 = 0, s12 = 0, s21 = 0, s22 = 0;
        #pragma unroll
        for (int d = 0; d < 10; ++d) {
            float wA = Wd1[d * 16 + j], wB = Wd1[(10 + d) * 16 + j];
            s11 += v1[d] * wA; s21 += v3[d] * wA;
            s12 += v2[d] * wB; s22 += v4[d] * wB;
        }
        float bb = bd1[j];
        hr1[j] = s11 + s12 + bb;   // [zx1, zs1]
        hr2[j] = s21 + s22 + bb;   // [zx2, zs2]
        hs1[j] = s11 + s22 + bb;   // [zx1, zs2]
        hs2[j] = s21 + s12 + bb;   // [zx2, zs1]
    }
    const float a0 = a[2 * r], a1 = a[2 * r + 1];
    float sr1x = 0, sr1a = 0, sr2x = 0, sr2a = 0, srs1 = 0, srs2 = 0;
    for (int j = 0; j < 128; ++j) {
        float w[16];
        #pragma unroll
        for (int k = 0; k < 16; ++k) w[k] = Wd2[k * 128 + j];
        float u1 = bd2[j], u2 = bd2[j], u3 = bd2[j], u4 = bd2[j];
        #pragma unroll
        for (int k = 0; k < 16; ++k) {
            u1 += hr1[k] * w[k]; u2 += hr2[k] * w[k];
            u3 += hs1[k] * w[k]; u4 += hs2[k] * w[k];
        }
        float sp1 = softplus_f(u1), sp2 = softplus_f(u2);
        float sp3 = softplus_f(u3), sp4 = softplus_f(u4);
        if (j < 126) {
            float t = sigmoid_f(x[(size_t)r * 126 + j]);
            sr1x += sp1 - t * u1; sr2x += sp2 - t * u2;
            srs1 += sp3 - t * u3; srs2 += sp4 - t * u4;
        } else {
            float av = (j == 126) ? a0 : a1;
            float t = sigmoid_f(av);
            sr1a += sp1 - t * u1; sr2a += sp2 - t * u2;
            srs1 += sp3 - t * u3;
            float t2 = sigmoid_f(1.0f - av);
            srs2 += sp4 - t2 * u4;
        }
    }
    __shared__ float red[256];
    bred_atomic(sr1x, red, &stat[ST_BCE + 0]);
    bred_atomic(sr1a, red, &stat[ST_BCE + 1]);
    bred_atomic(sr2x, red, &stat[ST_BCE + 2]);
    bred_atomic(sr2a, red, &stat[ST_BCE + 3]);
    bred_atomic(srs1, red, &stat[ST_BCE + 4]);
    bred_atomic(srs2, red, &stat[ST_BCE + 5]);
}

// ===========================================================================
// Final scalar assembly.
// ===========================================================================
__global__ void finalize_out_kernel(const double* __restrict__ st,
                                    float* __restrict__ out)
{
    if (threadIdx.x != 0 || blockIdx.x != 0) return;
    const double n = (double)N_;
    double dzx  = st[ST_KLD + 0] / n, dzs  = st[ST_KLD + 1] / n;
    double dxs1 = st[ST_KLD + 2] / n, dxs2 = st[ST_KLD + 3] / n;
    double Scl = st[ST_CL + 0], Scl2 = st[ST_CL + 1];
    double Sxcl = st[ST_CL + 2], Sx = st[ST_CL + 3];
    out[0] = (float)Scl;
    double xm = Sx / n, ym = Scl / n;
    double xv = (Sx - n * xm * xm) / (n - 1.0);      // x in {0,1} => Sxx == Sx
    double yv = (Scl2 - n * ym * ym) / (n - 1.0);
    double c  = fabs((Sxcl - n * xm * ym) / sqrt(xv * yv));
    out[1] = (float)((xm == 0.0) ? 0.0 : c);         // F1 = 1
    double tw = 0.0;
    for (int yy = 0; yy < 2; ++yy) {
        double c0 = st[ST_TWIN_CNT + yy * 2], c1 = st[ST_TWIN_CNT + yy * 2 + 1];
        double d = 0.0;
        for (int j = 0; j < 10; ++j) {
            double m0 = st[ST_TWIN_S1 + (yy * 2) * 10 + j]     / fmax(c0, 1.0);
            double m1 = st[ST_TWIN_S1 + (yy * 2 + 1) * 10 + j] / fmax(c1, 1.0);
            double w0 = (st[ST_TWIN_S2 + (yy * 2) * 10 + j]     - c0 * m0 * m0) / fmax(c0 - 1.0, 1.0);
            double w1 = (st[ST_TWIN_S2 + (yy * 2 + 1) * 10 + j] - c1 * m1 * m1) / fmax(c1 - 1.0, 1.0);
            d += (m0 - m1) * (m0 - m1) + (w0 - w1) * (w0 - w1);
        }
        if (c0 >= 2.0 && c1 >= 2.0) tw += d;
    }
    out[2] = (float)(0.1 * tw);
    out[3] = (float)(dzx + exp(-dzs) + exp(-dxs1) + exp(-dxs2));
    double recon = 0.5 * (st[ST_BCE + 0] + st[ST_BCE + 2]) / (n * 126.0)
                 + 0.5 * (st[ST_BCE + 1] + st[ST_BCE + 3]) / (n * 2.0);
    out[4] = (float)recon;
    out[5] = (float)(0.5 * (st[ST_BCE + 4] + st[ST_BCE + 5]) / (n * 128.0));
}

// ===========================================================================
extern "C" void kernel_launch(void* const* d_in, const int* in_sizes, int n_in,
                              void* d_out, int out_size, void* d_ws, size_t ws_size,
                              hipStream_t stream)
{
    const float* x   = (const float*)d_in[0];
    const float* a   = (const float*)d_in[1];
    const float* eps = (const float*)d_in[2];
    const int*   y   = (const int*)d_in[3];
    const float* W1  = (const float*)d_in[4];
    const float* b1  = (const float*)d_in[5];
    const float* g1  = (const float*)d_in[6];
    const float* be1 = (const float*)d_in[7];
    const float* g2  = (const float*)d_in[8];
    const float* be2 = (const float*)d_in[9];
    const float* W2  = (const float*)d_in[10];
    const float* b2  = (const float*)d_in[11];
    const float* Wc1 = (const float*)d_in[12];
    const float* bc1 = (const float*)d_in[13];
    const float* Wc2 = (const float*)d_in[14];
    const float* bc2 = (const float*)d_in[15];
    const float* Wd1 = (const float*)d_in[16];
    const float* bd1 = (const float*)d_in[17];
    const float* Wd2 = (const float*)d_in[18];
    const float* bd2 = (const float*)d_in[19];
    const float* Wn  = (const float*)d_in[20];
    const float* bnb = (const float*)d_in[21];

    char* ws = (char*)d_ws;
    double* st  = (double*)(ws + OFF_STATS);
    float* P    = (float*)(ws + OFF_PAR);
    float* bufA = (float*)(ws + OFF_BUFA);   // U1, later H1o2
    float* bufB = (float*)(ws + OFF_BUFB);   // U2, later H1c2 (in place)
    float* E1   = (float*)(ws + OFF_E1);
    float* E2   = (float*)(ws + OFF_E2);
    float* zx1  = (float*)(ws + OFF_ZX1);
    float* zs1  = (float*)(ws + OFF_ZS1);
    float* zx2  = (float*)(ws + OFF_ZX2);
    float* zs2  = (float*)(ws + OFF_ZS2);
    float* yp   = (float*)(ws + OFF_YP);
    const size_t NS = (size_t)N_ * 10;

    hipMemsetAsync(st, 0, 32768, stream);

    // ---- pass 1 ----
    gemm_plain_kernel<<<N_ / 128, 256, 0, stream>>>(x, DX_, W1, bufA);  // U1
    gemm_plain_kernel<<<N_ / 128, 256, 0, stream>>>(x, DX_, Wn, bufB);  // U2
    stats_p1_bn1_kernel<<<256, 256, 0, stream>>>(bufA, a, W1, b1, st + ST_P1BN1);
    finalize_bn_kernel<<<2, 128, 0, stream>>>(st + ST_P1BN1, g1, be1, P + PP1BN1);
    stats_p1_bn2_kernel<<<256, 256, 0, stream>>>(bufA, a, W1, b1, P + PP1BN1, st + ST_P1BN2);
    finalize_bn_kernel<<<2, 128, 0, stream>>>(st + ST_P1BN2, g2, be2, P + PP1BN2);
    tail_p1_kernel<<<N_ / 64, 256, 0, stream>>>(bufA, a, 0, W1, b1,
        P + PP1BN1, P + PP1BN1 + 128, P + PP1BN2, P + PP1BN2 + 128,
        W2, b2, eps + 0 * NS, zx1);
    tail_p1_kernel<<<N_ / 64, 256, 0, stream>>>(bufA, a, 1, W1, b1,
        P + PP1BN1 + 256, P + PP1BN1 + 384, P + PP1BN2 + 256, P + PP1BN2 + 384,
        W2, b2, eps + 2 * NS, zx2);
    cla_argmax_kernel<<<N_ / 256, 256, 0, stream>>>(zx1, zx2, Wc1, bc1, Wc2, bc2, yp);

    // ---- pass 2 ----
    gemm_front_kernel<<<N_ / 128, 256, 0, stream>>>(bufB, a, yp, Wn, bnb, 0, W1, b1, bufA);
    gemm_front_kernel<<<N_ / 128, 256, 0, stream>>>(bufB, a, yp, Wn, bnb, 1, W1, b1, bufB);
    stats_p2_bn1_kernel<<<256, 256, 0, stream>>>(bufA, bufB, st + ST_P2BN1);
    finalize_bn_kernel<<<2, 128, 0, stream>>>(st + ST_P2BN1, g1, be1, P + PP2BN1);
    stats_p2_bn2_kernel<<<256, 256, 0, stream>>>(bufA, bufB, P + PP2BN1, st + ST_P2BN2);
    finalize_bn_kernel<<<2, 128, 0, stream>>>(st + ST_P2BN2, g2, be2, P + PP2BN2);
    tail_p2_kernel<<<N_ / 64, 256, 0, stream>>>(bufA,
        P + PP2BN1, P + PP2BN1 + 128, P + PP2BN2, P + PP2BN2 + 128, W2, b2, E1);
    tail_p2_kernel<<<N_ / 64, 256, 0, stream>>>(bufB,
        P + PP2BN1 + 256, P + PP2BN1 + 384, P + PP2BN2 + 256, P + PP2BN2 + 384, W2, b2, E2);
    latents_kernel<<<N_ / 256, 256, 0, stream>>>(E1, E2, eps, y, a,
        Wc1, bc1, Wc2, bc2, zx1, zs1, zx2, zs2, st);
    dec_bce_kernel<<<N_ / 256, 256, 0, stream>>>(zx1, zs1, zx2, zs2, x, a,
        Wd1, bd1, Wd2, bd2, st);
    finalize_out_kernel<<<1, 64, 0, stream>>>(st, (float*)d_out);
}

// Round 5
// 2754.612 us; speedup vs baseline: 1.1880x; 1.1880x over previous
//
#include <hip/hip_runtime.h>
#include <hip/hip_bf16.h>
#include <math.h>

// ---------------------------------------------------------------------------
// FairRep forward on MI355X. fp32 throughout (no fp32 MFMA on CDNA4).
// R4 changes vs R3 baseline (3272 us, dec_bce 590 us VALU-bound):
//  - native-math intrinsics (__expf/__logf/v_rcp) in all hot kernels
//  - dec_bce rewritten: 8 threads/row, LDS-staged h + Wd2, butterfly reduce,
//    64-way binned global atomics
//  - stats kernels grid 256 -> 1024 (occupancy was 1 block/CU)
//  - latents: fused 8-value butterfly reduction (was 8x bred_atomic)
// ---------------------------------------------------------------------------

#define N_      262144
#define DX_     126

// ---- workspace layout (bytes) ----
static const size_t OFF_STATS = 0;                      // 4096 doubles (32 KB)
static const size_t OFF_PAR   = 32768;                  // 4096 floats (16 KB)
static const size_t OFF_BUFA  = 65536;                  // N*128 f32 (U1 / H1o2)
static const size_t SZ_NH     = (size_t)N_ * 128 * 4;
static const size_t OFF_BUFB  = OFF_BUFA + SZ_NH;       // N*128 f32 (U2 / H1c2)
static const size_t OFF_E1    = OFF_BUFB + SZ_NH;       // N*40
static const size_t OFF_E2    = OFF_E1 + (size_t)N_*40*4;
static const size_t OFF_ZX1   = OFF_E2 + (size_t)N_*40*4;
static const size_t OFF_ZS1   = OFF_ZX1 + (size_t)N_*10*4;
static const size_t OFF_ZX2   = OFF_ZS1 + (size_t)N_*10*4;
static const size_t OFF_ZS2   = OFF_ZX2 + (size_t)N_*10*4;
static const size_t OFF_YP    = OFF_ZS2 + (size_t)N_*10*4;

// ---- stats region (double indices) ----
#define ST_P1BN1    0     // [o: sum 0..127, sumsq 128..255][c: 256..511]
#define ST_P1BN2    512
#define ST_P2BN1    1024
#define ST_P2BN2    1536
#define ST_KLD      2048  // dzx, dzs, dxs1, dxs2
#define ST_CL       2052  // Scl, Scl2, Sxcl, Sx
#define ST_TWIN_CNT 2056  // 4
#define ST_TWIN_S1  2060  // 40
#define ST_TWIN_S2  2100  // 40
#define ST_BCE_PART 2176  // 6 x 64 bins (r1x, r1a, r2x, r2a, rs1, rs2)

// ---- bn param region (float indices): [A(128) B(128)] per branch ----
#define PP1BN1  0
#define PP1BN2  512
#define PP2BN1  1024
#define PP2BN2  1536

__device__ __forceinline__ float softplus_f(float u) {
    return fmaxf(u, 0.0f) + __logf(1.0f + __expf(-fabsf(u)));
}
__device__ __forceinline__ float sigmoid_f(float u) {
    return __builtin_amdgcn_rcpf(1.0f + __expf(-u));
}

// ===========================================================================
// GEMM: C(N x 128) = A(N x K) @ W(K x 128), row-major, no bias.
// ===========================================================================
#define BMg 128
#define BKg 32

__global__ __launch_bounds__(256, 4) void gemm_plain_kernel(
    const float* __restrict__ A, int K, const float* __restrict__ W,
    float* __restrict__ C)
{
    __shared__ __align__(16) float As[BKg][BMg + 4];
    __shared__ __align__(16) float Bs[BKg][128];
    const int row0 = blockIdx.x * BMg;
    const int tid  = threadIdx.x;
    const int tr   = (tid / 16) * 8;
    const int tc   = (tid % 16) * 8;
    float acc[8][8] = {};
    const int nk = (K + BKg - 1) / BKg;
    for (int kc = 0; kc < nk; ++kc) {
        const int k0 = kc * BKg;
        #pragma unroll
        for (int i = 0; i < 16; ++i) {
            int idx = tid + i * 256;
            int m = idx / BKg, k = idx % BKg;
            int gk = k0 + k;
            As[k][m] = (gk < K) ? A[(size_t)(row0 + m) * K + gk] : 0.0f;
        }
        #pragma unroll
        for (int i = 0; i < 16; ++i) {
            int idx = tid + i * 256;
            int k = idx / 128, n = idx % 128;
            int gk = k0 + k;
            Bs[k][n] = (gk < K) ? W[(size_t)gk * 128 + n] : 0.0f;
        }
        __syncthreads();
        #pragma unroll
        for (int k = 0; k < BKg; ++k) {
            float4 a0 = *(const float4*)&As[k][tr];
            float4 a1 = *(const float4*)&As[k][tr + 4];
            float4 b0 = *(const float4*)&Bs[k][tc];
            float4 b1v = *(const float4*)&Bs[k][tc + 4];
            float av[8] = {a0.x, a0.y, a0.z, a0.w, a1.x, a1.y, a1.z, a1.w};
            float bv[8] = {b0.x, b0.y, b0.z, b0.w, b1v.x, b1v.y, b1v.z, b1v.w};
            #pragma unroll
            for (int i = 0; i < 8; ++i)
                #pragma unroll
                for (int j = 0; j < 8; ++j)
                    acc[i][j] = fmaf(av[i], bv[j], acc[i][j]);
        }
        __syncthreads();
    }
    #pragma unroll
    for (int i = 0; i < 8; ++i) {
        float4 s0 = {acc[i][0], acc[i][1], acc[i][2], acc[i][3]};
        float4 s1 = {acc[i][4], acc[i][5], acc[i][6], acc[i][7]};
        size_t base = (size_t)(row0 + tr + i) * 128 + tc;
        *(float4*)&C[base]     = s0;
        *(float4*)&C[base + 4] = s1;
    }
}

// ===========================================================================
// Pass-2 front GEMM: A = relu(U2 + a0*Wn[126] + a1*Wn[127] + yp*Wn[128] + bnb)
// C = A @ W1 + b1.  K=128.  In-place capable (branch c) -> no restrict.
// ===========================================================================
__global__ __launch_bounds__(256, 4) void gemm_front_kernel(
    const float* U2, const float* __restrict__ a,
    const float* __restrict__ ypred, const float* __restrict__ Wn,
    const float* __restrict__ bnb, int conj,
    const float* __restrict__ W1, const float* __restrict__ b1,
    float* Cout)
{
    __shared__ __align__(16) float As[BKg][BMg + 4];
    __shared__ __align__(16) float Bs[BKg][128];
    __shared__ float ra0[BMg], ra1[BMg], ryp[BMg];
    __shared__ float w6s[128], w7s[128], w8s[128], bns[128];
    const int row0 = blockIdx.x * BMg;
    const int tid  = threadIdx.x;
    if (tid < 128) {
        int r = row0 + tid;
        float a0 = a[2 * r], a1 = a[2 * r + 1];
        if (conj) { a0 = 1.0f - a0; a1 = 1.0f - a1; }
        ra0[tid] = a0; ra1[tid] = a1; ryp[tid] = ypred[r];
        w6s[tid] = Wn[126 * 128 + tid];
        w7s[tid] = Wn[127 * 128 + tid];
        w8s[tid] = Wn[128 * 128 + tid];
        bns[tid] = bnb[tid];
    }
    __syncthreads();
    const int tr = (tid / 16) * 8;
    const int tc = (tid % 16) * 8;
    float acc[8][8] = {};
    for (int kc = 0; kc < 4; ++kc) {
        const int k0 = kc * BKg;
        #pragma unroll
        for (int i = 0; i < 16; ++i) {
            int idx = tid + i * 256;
            int m = idx / BKg, k = idx % BKg;
            int gk = k0 + k;
            float u = U2[(size_t)(row0 + m) * 128 + gk];
            float v = u + ra0[m] * w6s[gk] + ra1[m] * w7s[gk]
                        + ryp[m] * w8s[gk] + bns[gk];
            As[k][m] = fmaxf(v, 0.0f);
        }
        #pragma unroll
        for (int i = 0; i < 16; ++i) {
            int idx = tid + i * 256;
            int k = idx / 128, n = idx % 128;
            Bs[k][n] = W1[(size_t)(k0 + k) * 128 + n];
        }
        __syncthreads();
        #pragma unroll
        for (int k = 0; k < BKg; ++k) {
            float4 a0 = *(const float4*)&As[k][tr];
            float4 a1 = *(const float4*)&As[k][tr + 4];
            float4 b0 = *(const float4*)&Bs[k][tc];
            float4 b1v = *(const float4*)&Bs[k][tc + 4];
            float av[8] = {a0.x, a0.y, a0.z, a0.w, a1.x, a1.y, a1.z, a1.w};
            float bv[8] = {b0.x, b0.y, b0.z, b0.w, b1v.x, b1v.y, b1v.z, b1v.w};
            #pragma unroll
            for (int i = 0; i < 8; ++i)
                #pragma unroll
                for (int j = 0; j < 8; ++j)
                    acc[i][j] = fmaf(av[i], bv[j], acc[i][j]);
        }
        __syncthreads();
    }
    float bias[8];
    #pragma unroll
    for (int j = 0; j < 8; ++j) bias[j] = b1[tc + j];
    #pragma unroll
    for (int i = 0; i < 8; ++i) {
        float4 s0 = {acc[i][0] + bias[0], acc[i][1] + bias[1],
                     acc[i][2] + bias[2], acc[i][3] + bias[3]};
        float4 s1 = {acc[i][4] + bias[4], acc[i][5] + bias[5],
                     acc[i][6] + bias[6], acc[i][7] + bias[7]};
        size_t base = (size_t)(row0 + tr + i) * 128 + tc;
        *(float4*)&Cout[base]     = s0;
        *(float4*)&Cout[base + 4] = s1;
    }
}

// ===========================================================================
// Pass-1 BN1 stats. grid 1024; thread=(col,half); 128 rows each.
// ===========================================================================
__global__ __launch_bounds__(256) void stats_p1_bn1_kernel(
    const float* __restrict__ U1, const float* __restrict__ a,
    const float* __restrict__ W1, const float* __restrict__ b1,
    double* __restrict__ stat)
{
    const int tid = threadIdx.x;
    const int col = tid & 127, half = tid >> 7;
    const int r0 = blockIdx.x * 256 + half * 128;
    const float w6 = W1[126 * 128 + col], w7 = W1[127 * 128 + col];
    const float bb = b1[col];
    double dso = 0, dqo = 0, dsc = 0, dqc = 0;
    for (int i0 = 0; i0 < 128; i0 += 64) {
        float so = 0, qo = 0, sc = 0, qc = 0;
        for (int i = i0; i < i0 + 64; ++i) {
            int r = r0 + i;
            float u  = U1[(size_t)r * 128 + col];
            float a0 = a[2 * r], a1 = a[2 * r + 1];
            float ho = u + a0 * w6 + a1 * w7 + bb;
            float hc = u + (1.0f - a0) * w6 + (1.0f - a1) * w7 + bb;
            so += ho; qo += ho * ho; sc += hc; qc += hc * hc;
        }
        dso += so; dqo += qo; dsc += sc; dqc += qc;
    }
    __shared__ double red[4][128];
    if (half == 1) { red[0][col]=dso; red[1][col]=dqo; red[2][col]=dsc; red[3][col]=dqc; }
    __syncthreads();
    if (half == 0) {
        atomicAdd(&stat[col],       dso + red[0][col]);
        atomicAdd(&stat[128 + col], dqo + red[1][col]);
        atomicAdd(&stat[256 + col], dsc + red[2][col]);
        atomicAdd(&stat[384 + col], dqc + red[3][col]);
    }
}

// Pass-1 BN2 stats. grid 1024.
__global__ __launch_bounds__(256) void stats_p1_bn2_kernel(
    const float* __restrict__ U1, const float* __restrict__ a,
    const float* __restrict__ W1, const float* __restrict__ b1,
    const float* __restrict__ Pbn1, double* __restrict__ stat)
{
    const int tid = threadIdx.x;
    const int col = tid & 127, half = tid >> 7;
    const int r0 = blockIdx.x * 256 + half * 128;
    const float w6 = W1[126 * 128 + col], w7 = W1[127 * 128 + col];
    const float bb = b1[col];
    const float A1o = Pbn1[col],       B1o = Pbn1[128 + col];
    const float A1c = Pbn1[256 + col], B1c = Pbn1[384 + col];
    double dso = 0, dqo = 0, dsc = 0, dqc = 0;
    for (int i0 = 0; i0 < 128; i0 += 64) {
        float so = 0, qo = 0, sc = 0, qc = 0;
        for (int i = i0; i < i0 + 64; ++i) {
            int r = r0 + i;
            float u  = U1[(size_t)r * 128 + col];
            float a0 = a[2 * r], a1 = a[2 * r + 1];
            float ho = u + a0 * w6 + a1 * w7 + bb;
            float hc = u + (1.0f - a0) * w6 + (1.0f - a1) * w7 + bb;
            float r1o = fmaxf(fmaf(A1o, ho, B1o), 0.0f);
            float r1c = fmaxf(fmaf(A1c, hc, B1c), 0.0f);
            so += r1o; qo += r1o * r1o; sc += r1c; qc += r1c * r1c;
        }
        dso += so; dqo += qo; dsc += sc; dqc += qc;
    }
    __shared__ double red[4][128];
    if (half == 1) { red[0][col]=dso; red[1][col]=dqo; red[2][col]=dsc; red[3][col]=dqc; }
    __syncthreads();
    if (half == 0) {
        atomicAdd(&stat[col],       dso + red[0][col]);
        atomicAdd(&stat[128 + col], dqo + red[1][col]);
        atomicAdd(&stat[256 + col], dsc + red[2][col]);
        atomicAdd(&stat[384 + col], dqc + red[3][col]);
    }
}

// Pass-2 BN1 stats. grid 1024; thread=(col,branch); 256 rows each.
__global__ __launch_bounds__(256) void stats_p2_bn1_kernel(
    const float* __restrict__ H1o, const float* __restrict__ H1c,
    double* __restrict__ stat)
{
    const int tid = threadIdx.x;
    const int col = tid & 127, br = tid >> 7;
    const float* H = br ? H1c : H1o;
    const int r0 = blockIdx.x * 256;
    double ds = 0, dq = 0;
    for (int i0 = 0; i0 < 256; i0 += 64) {
        float s = 0, q = 0;
        for (int i = i0; i < i0 + 64; ++i) {
            float h = H[(size_t)(r0 + i) * 128 + col];
            s += h; q += h * h;
        }
        ds += s; dq += q;
    }
    atomicAdd(&stat[br * 256 + col], ds);
    atomicAdd(&stat[br * 256 + 128 + col], dq);
}

__global__ __launch_bounds__(256) void stats_p2_bn2_kernel(
    const float* __restrict__ H1o, const float* __restrict__ H1c,
    const float* __restrict__ Pbn1, double* __restrict__ stat)
{
    const int tid = threadIdx.x;
    const int col = tid & 127, br = tid >> 7;
    const float* H = br ? H1c : H1o;
    const float A1 = Pbn1[br * 256 + col], B1 = Pbn1[br * 256 + 128 + col];
    const int r0 = blockIdx.x * 256;
    double ds = 0, dq = 0;
    for (int i0 = 0; i0 < 256; i0 += 64) {
        float s = 0, q = 0;
        for (int i = i0; i < i0 + 64; ++i) {
            float h = H[(size_t)(r0 + i) * 128 + col];
            float r1 = fmaxf(fmaf(A1, h, B1), 0.0f);
            s += r1; q += r1 * r1;
        }
        ds += s; dq += q;
    }
    atomicAdd(&stat[br * 256 + col], ds);
    atomicAdd(&stat[br * 256 + 128 + col], dq);
}

// grid 2 (branch), 128 threads: mu/var -> scale A, shift B
__global__ void finalize_bn_kernel(const double* __restrict__ stat,
                                   const float* __restrict__ g,
                                   const float* __restrict__ be,
                                   float* __restrict__ Pout)
{
    const int br = blockIdx.x, j = threadIdx.x;
    double s = stat[br * 256 + j], q = stat[br * 256 + 128 + j];
    double mu = s / (double)N_;
    double var = q / (double)N_ - mu * mu;
    float rstd = (float)rsqrt(var + 1e-5);
    float A = g[j] * rstd;
    float B = be[j] - (float)mu * A;
    Pout[br * 256 + j] = A;
    Pout[br * 256 + 128 + j] = B;
}

// ===========================================================================
// Pass-1 tail. 64 rows/block, 256 threads.
// ===========================================================================
__global__ __launch_bounds__(256) void tail_p1_kernel(
    const float* __restrict__ U1, const float* __restrict__ a, int conj,
    const float* __restrict__ W1, const float* __restrict__ b1,
    const float* __restrict__ A1p, const float* __restrict__ B1p,
    const float* __restrict__ A2p, const float* __restrict__ B2p,
    const float* __restrict__ W2, const float* __restrict__ b2,
    const float* __restrict__ epsk, float* __restrict__ zout)
{
    __shared__ float As[128][69];
    __shared__ float outs[64][24];
    const int row0 = blockIdx.x * 64;
    const int tid  = threadIdx.x;
    for (int i = tid; i < 64 * 128; i += 256) {
        int r = i >> 7, k = i & 127;
        int gr = row0 + r;
        float a0 = a[2 * gr], a1 = a[2 * gr + 1];
        if (conj) { a0 = 1.0f - a0; a1 = 1.0f - a1; }
        float h = U1[(size_t)gr * 128 + k] + a0 * W1[126 * 128 + k]
                + a1 * W1[127 * 128 + k] + b1[k];
        float r1 = fmaxf(fmaf(A1p[k], h, B1p[k]), 0.0f);
        float r2 = fmaxf(fmaf(A2p[k], r1, B2p[k]), 0.0f);
        As[k][r] = r2;
    }
    __syncthreads();
    const int row = tid & 63;
    const int cg  = tid >> 6;
    const int wbase = __builtin_amdgcn_readfirstlane((cg < 2) ? cg * 5 : 10 + cg * 5);
    float acc[5] = {};
    for (int k = 0; k < 128; ++k) {
        float av = As[k][row];
        #pragma unroll
        for (int c = 0; c < 5; ++c)
            acc[c] = fmaf(av, W2[k * 40 + wbase + c], acc[c]);
    }
    #pragma unroll
    for (int c = 0; c < 5; ++c)
        outs[row][cg * 5 + c] = acc[c] + b2[wbase + c];
    __syncthreads();
    if (tid < 128) {
        int r = tid & 63, dg = tid >> 6;
        int gr = row0 + r;
        #pragma unroll
        for (int c = 0; c < 5; ++c) {
            int d = dg * 5 + c;
            float mx = outs[r][d], lx = outs[r][10 + d];
            zout[(size_t)gr * 10 + d] =
                epsk[(size_t)gr * 10 + d] * __expf(0.5f * lx) + mx;
        }
    }
}

// Pass-2 tail: full 40-col output E = r2@W2 + b2.
__global__ __launch_bounds__(256) void tail_p2_kernel(
    const float* __restrict__ H1,
    const float* __restrict__ A1p, const float* __restrict__ B1p,
    const float* __restrict__ A2p, const float* __restrict__ B2p,
    const float* __restrict__ W2, const float* __restrict__ b2,
    float* __restrict__ E)
{
    __shared__ float As[128][69];
    __shared__ float outs[64][44];
    const int row0 = blockIdx.x * 64;
    const int tid  = threadIdx.x;
    for (int i = tid; i < 64 * 128; i += 256) {
        int r = i >> 7, k = i & 127;
        float h = H1[(size_t)(row0 + r) * 128 + k];
        float r1 = fmaxf(fmaf(A1p[k], h, B1p[k]), 0.0f);
        float r2 = fmaxf(fmaf(A2p[k], r1, B2p[k]), 0.0f);
        As[k][r] = r2;
    }
    __syncthreads();
    const int row = tid & 63;
    const int cg  = tid >> 6;
    const int wbase = __builtin_amdgcn_readfirstlane(cg * 10);
    float acc[10] = {};
    for (int k = 0; k < 128; ++k) {
        float av = As[k][row];
        #pragma unroll
        for (int c = 0; c < 10; ++c)
            acc[c] = fmaf(av, W2[k * 40 + wbase + c], acc[c]);
    }
    #pragma unroll
    for (int c = 0; c < 10; ++c)
        outs[row][wbase + c] = acc[c] + b2[wbase + c];
    __syncthreads();
    size_t base = (size_t)row0 * 40;
    for (int i = tid; i < 64 * 40; i += 256)
        E[base + i] = outs[i / 40][i % 40];
}

// ===========================================================================
// cla(zx1)+cla(zx2) argmax -> y_pred (float 0/1)
// ===========================================================================
__global__ __launch_bounds__(256) void cla_argmax_kernel(
    const float* __restrict__ zx1, const float* __restrict__ zx2,
    const float* __restrict__ Wc1, const float* __restrict__ bc1,
    const float* __restrict__ Wc2, const float* __restrict__ bc2,
    float* __restrict__ ypred)
{
    const int r = blockIdx.x * 256 + threadIdx.x;
    float z1[10], z2[10];
    #pragma unroll
    for (int d = 0; d < 10; ++d) {
        z1[d] = zx1[(size_t)r * 10 + d];
        z2[d] = zx2[(size_t)r * 10 + d];
    }
    float lg0 = 2.0f * bc2[0], lg1 = 2.0f * bc2[1];
    #pragma unroll
    for (int j = 0; j < 32; ++j) {
        float s1 = bc1[j], s2 = bc1[j];
        #pragma unroll
        for (int d = 0; d < 10; ++d) {
            float w = Wc1[d * 32 + j];
            s1 += z1[d] * w; s2 += z2[d] * w;
        }
        float s = s1 + s2;
        lg0 += s * Wc2[j * 2 + 0];
        lg1 += s * Wc2[j * 2 + 1];
    }
    ypred[r] = (lg1 > lg0) ? 1.0f : 0.0f;
}

// ===========================================================================
// latents: KLDs, z samples, cl (ce+moments), twin group stats.
// ===========================================================================
__device__ __forceinline__ float sym10(const float* m1, const float* l1,
                                       const float* m2, const float* l2)
{
    float t12 = 0, t21 = 0;
    #pragma unroll
    for (int j = 0; j < 10; ++j) {
        float dl = l1[j] - l2[j];
        float md = m1[j] - m2[j]; md *= md;
        t12 += -dl + __expf(dl)  + md * __expf(-l2[j]);
        t21 +=  dl + __expf(-dl) + md * __expf(-l1[j]);
    }
    return 0.025f * ((t12 - 10.0f) + (t21 - 10.0f));
}

__device__ __forceinline__ float ce2_of(const float* z, int yv,
    const float* Wc1, const float* bc1, const float* Wc2, const float* bc2)
{
    float lg0 = bc2[0], lg1 = bc2[1];
    #pragma unroll
    for (int j = 0; j < 32; ++j) {
        float s = bc1[j];
        #pragma unroll
        for (int d = 0; d < 10; ++d) s += z[d] * Wc1[d * 32 + j];
        lg0 += s * Wc2[j * 2 + 0];
        lg1 += s * Wc2[j * 2 + 1];
    }
    float m = fmaxf(lg0, lg1);
    float lse = m + __logf(__expf(lg0 - m) + __expf(lg1 - m));
    float ly = yv ? lg1 : lg0;
    return -(ly - lse);
}

__global__ __launch_bounds__(256) void latents_kernel(
    const float* __restrict__ E1, const float* __restrict__ E2,
    const float* __restrict__ eps,
    const int* __restrict__ y, const float* __restrict__ a,
    const float* __restrict__ Wc1, const float* __restrict__ bc1,
    const float* __restrict__ Wc2, const float* __restrict__ bc2,
    float* __restrict__ zx1, float* __restrict__ zs1,
    float* __restrict__ zx2, float* __restrict__ zs2,
    double* __restrict__ stat)
{
    __shared__ float tw_cnt[4], tw_s1[40], tw_s2[40];
    __shared__ float redw[4][8];
    const int tid = threadIdx.x;
    if (tid < 4) tw_cnt[tid] = 0.0f;
    if (tid < 40) { tw_s1[tid] = 0.0f; tw_s2[tid] = 0.0f; }
    __syncthreads();

    const int r = blockIdx.x * 256 + tid;
    const size_t NS = (size_t)N_ * 10;
    float e1[40], e2[40];
    #pragma unroll
    for (int i = 0; i < 40; ++i) {
        e1[i] = E1[(size_t)r * 40 + i];
        e2[i] = E2[(size_t)r * 40 + i];
    }
    // layout: [mx 0..9 | ms 10..19 | lx 20..29 | ls 30..39]
    float s_dzx  = sym10(e1 + 0,  e1 + 20, e2 + 0,  e2 + 20);
    float s_dzs  = sym10(e1 + 10, e1 + 30, e2 + 10, e2 + 30);
    float s_dxs1 = sym10(e1 + 0,  e1 + 20, e1 + 10, e1 + 30);
    float s_dxs2 = sym10(e2 + 0,  e2 + 20, e2 + 10, e2 + 30);

    float z1[10], z2[10];
    #pragma unroll
    for (int d = 0; d < 10; ++d) {
        size_t rd = (size_t)r * 10 + d;
        float v1 = eps[4 * NS + rd] * __expf(0.5f * e1[20 + d]) + e1[d];
        float t1 = eps[5 * NS + rd] * __expf(0.5f * e1[30 + d]) + e1[10 + d];
        float v2 = eps[6 * NS + rd] * __expf(0.5f * e2[20 + d]) + e2[d];
        float t2 = eps[7 * NS + rd] * __expf(0.5f * e2[30 + d]) + e2[10 + d];
        zx1[rd] = v1; zs1[rd] = t1; zx2[rd] = v2; zs2[rd] = t2;
        z1[d] = v1; z2[d] = v2;
    }

    const int yv = y[r];
    float ce1 = ce2_of(z1, yv, Wc1, bc1, Wc2, bc2);
    float ce2 = ce2_of(z2, yv, Wc1, bc1, Wc2, bc2);
    float cl = 0.5f * (ce1 + ce2);
    float atag = (a[2 * r + 1] > a[2 * r]) ? 1.0f : 0.0f;

    // twin group stats on z1 (LDS atomics)
    int gid = yv * 2 + (int)atag;
    atomicAdd(&tw_cnt[gid], 1.0f);
    #pragma unroll
    for (int d = 0; d < 10; ++d) {
        atomicAdd(&tw_s1[gid * 10 + d], z1[d]);
        atomicAdd(&tw_s2[gid * 10 + d], z1[d] * z1[d]);
    }

    // fused 8-value butterfly reduction -> stat[ST_KLD..ST_CL+3]
    float vals[8] = {s_dzx, s_dzs, s_dxs1, s_dxs2, cl, cl * cl, atag * cl, atag};
    #pragma unroll
    for (int v = 0; v < 8; ++v) {
        float sv = vals[v];
        #pragma unroll
        for (int off = 1; off < 64; off <<= 1) sv += __shfl_xor(sv, off);
        vals[v] = sv;
    }
    const int wave = tid >> 6;
    if ((tid & 63) == 0) {
        #pragma unroll
        for (int v = 0; v < 8; ++v) redw[wave][v] = vals[v];
    }
    __syncthreads();
    if (tid < 8) {
        float s = redw[0][tid] + redw[1][tid] + redw[2][tid] + redw[3][tid];
        atomicAdd(&stat[ST_KLD + tid], (double)s);
    }
    if (tid < 4)  atomicAdd(&stat[ST_TWIN_CNT + tid], (double)tw_cnt[tid]);
    if (tid < 40) {
        atomicAdd(&stat[ST_TWIN_S1 + tid], (double)tw_s1[tid]);
        atomicAdd(&stat[ST_TWIN_S2 + tid], (double)tw_s2[tid]);
    }
}

// ===========================================================================
// Decoder + BCE. 32 rows/block, 8 threads per row (column-split), LDS-staged
// h and Wd2, butterfly reduce, 64-way binned global atomics.
// ===========================================================================
#define DB_ROWS 32

__global__ __launch_bounds__(256) void dec_bce_kernel(
    const float* __restrict__ zx1, const float* __restrict__ zs1,
    const float* __restrict__ zx2, const float* __restrict__ zs2,
    const float* __restrict__ x, const float* __restrict__ a,
    const float* __restrict__ Wd1, const float* __restrict__ bd1,
    const float* __restrict__ Wd2, const float* __restrict__ bd2,
    double* __restrict__ stat)
{
    __shared__ float zsh[DB_ROWS][40];
    __shared__ float hsh[DB_ROWS][68];   // [row][c*16+k], pad 68 breaks conflicts
    __shared__ float wsh[16 * 128];
    __shared__ float bsh[128];
    __shared__ float ash[DB_ROWS][2];
    __shared__ float redw[4][8];
    const int t = threadIdx.x;
    const int row0 = blockIdx.x * DB_ROWS;

    // ---- stage z, Wd2, bd2, a ----
    for (int i = t; i < DB_ROWS * 40; i += 256) {
        int rr = i / 40, d = i % 40;
        const float* src = (d < 10) ? zx1 : (d < 20) ? zs1 : (d < 30) ? zx2 : zs2;
        zsh[rr][d] = src[(size_t)(row0 + rr) * 10 + (d % 10)];
    }
    for (int i = t; i < 2048; i += 256) wsh[i] = Wd2[i];
    if (t < 128) bsh[t] = bd2[t];
    if (t < 64) { int rr = t >> 1, c = t & 1; ash[rr][c] = a[2 * (row0 + rr) + c]; }
    __syncthreads();

    // ---- h = z @ Wd1 + bd1 per combo: c0=[zx1,zs1] c1=[zx2,zs2] c2=[zx1,zs2] c3=[zx2,zs1]
    for (int i = t; i < DB_ROWS * 64; i += 256) {
        int rr = i >> 6, ck = i & 63, c = ck >> 4, k = ck & 15;
        int oA = (c == 0 || c == 2) ? 0 : 20;
        int oB = (c == 0 || c == 3) ? 10 : 30;
        float s = bd1[k];
        #pragma unroll
        for (int d = 0; d < 10; ++d) {
            s = fmaf(zsh[rr][oA + d], Wd1[d * 16 + k], s);
            s = fmaf(zsh[rr][oB + d], Wd1[(10 + d) * 16 + k], s);
        }
        hsh[rr][c * 16 + k] = s;
    }
    __syncthreads();

    // ---- column loop: thread (row, jl) handles j = jl + 8*i ----
    const int rloc = t >> 3, jl = t & 7;
    const int gr = row0 + rloc;
    float h0[16], h1[16], h2[16], h3[16];
    #pragma unroll
    for (int k = 0; k < 16; ++k) {
        h0[k] = hsh[rloc][k];      h1[k] = hsh[rloc][16 + k];
        h2[k] = hsh[rloc][32 + k]; h3[k] = hsh[rloc][48 + k];
    }
    const float a0 = ash[rloc][0], a1 = ash[rloc][1];
    float s1x = 0, s1a = 0, s2x = 0, s2a = 0, ss1 = 0, ss2 = 0;
    #pragma unroll 4
    for (int i = 0; i < 16; ++i) {
        const int j = jl + 8 * i;
        float u0 = bsh[j], u1 = bsh[j], u2 = bsh[j], u3 = bsh[j];
        #pragma unroll
        for (int k = 0; k < 16; ++k) {
            float w = wsh[k * 128 + j];
            u0 = fmaf(h0[k], w, u0); u1 = fmaf(h1[k], w, u1);
            u2 = fmaf(h2[k], w, u2); u3 = fmaf(h3[k], w, u3);
        }
        float sp0 = softplus_f(u0), sp1 = softplus_f(u1);
        float sp2 = softplus_f(u2), sp3 = softplus_f(u3);
        if (j < 126) {
            float tt = sigmoid_f(x[(size_t)gr * 126 + j]);
            s1x += sp0 - tt * u0; s2x += sp1 - tt * u1;
            ss1 += sp2 - tt * u2; ss2 += sp3 - tt * u3;
        } else {
            float av = (j == 126) ? a0 : a1;
            float tt = sigmoid_f(av);
            s1a += sp0 - tt * u0; s2a += sp1 - tt * u1;
            ss1 += sp2 - tt * u2;
            float t2 = sigmoid_f(1.0f - av);
            ss2 += sp3 - t2 * u3;
        }
    }

    // ---- reduce 6 sums over the block ----
    float vals[6] = {s1x, s1a, s2x, s2a, ss1, ss2};
    #pragma unroll
    for (int v = 0; v < 6; ++v) {
        float sv = vals[v];
        #pragma unroll
        for (int off = 1; off < 64; off <<= 1) sv += __shfl_xor(sv, off);
        vals[v] = sv;
    }
    const int wave = t >> 6;
    if ((t & 63) == 0) {
        #pragma unroll
        for (int v = 0; v < 6; ++v) redw[wave][v] = vals[v];
    }
    __syncthreads();
    if (t < 6) {
        float s = redw[0][t] + redw[1][t] + redw[2][t] + redw[3][t];
        atomicAdd(&stat[ST_BCE_PART + t * 64 + (blockIdx.x & 63)], (double)s);
    }
}

// ===========================================================================
// Final scalar assembly.
// ===========================================================================
__global__ void finalize_out_kernel(const double* __restrict__ st,
                                    float* __restrict__ out)
{
    if (threadIdx.x != 0 || blockIdx.x != 0) return;
    const double n = (double)N_;
    double bce[6];
    for (int v = 0; v < 6; ++v) {
        double s = 0;
        for (int b = 0; b < 64; ++b) s += st[ST_BCE_PART + v * 64 + b];
        bce[v] = s;
    }
    double dzx  = st[ST_KLD + 0] / n, dzs  = st[ST_KLD + 1] / n;
    double dxs1 = st[ST_KLD + 2] / n, dxs2 = st[ST_KLD + 3] / n;
    double Scl = st[ST_CL + 0], Scl2 = st[ST_CL + 1];
    double Sxcl = st[ST_CL + 2], Sx = st[ST_CL + 3];
    out[0] = (float)Scl;
    double xm = Sx / n, ym = Scl / n;
    double xv = (Sx - n * xm * xm) / (n - 1.0);
    double yv = (Scl2 - n * ym * ym) / (n - 1.0);
    double c  = fabs((Sxcl - n * xm * ym) / sqrt(xv * yv));
    out[1] = (float)((xm == 0.0) ? 0.0 : c);
    double tw = 0.0;
    for (int yy = 0; yy < 2; ++yy) {
        double c0 = st[ST_TWIN_CNT + yy * 2], c1 = st[ST_TWIN_CNT + yy * 2 + 1];
        double d = 0.0;
        for (int j = 0; j < 10; ++j) {
            double m0 = st[ST_TWIN_S1 + (yy * 2) * 10 + j]     / fmax(c0, 1.0);
            double m1 = st[ST_TWIN_S1 + (yy * 2 + 1) * 10 + j] / fmax(c1, 1.0);
            double w0 = (st[ST_TWIN_S2 + (yy * 2) * 10 + j]     - c0 * m0 * m0) / fmax(c0 - 1.0, 1.0);
            double w1 = (st[ST_TWIN_S2 + (yy * 2 + 1) * 10 + j] - c1 * m1 * m1) / fmax(c1 - 1.0, 1.0);
            d += (m0 - m1) * (m0 - m1) + (w0 - w1) * (w0 - w1);
        }
        if (c0 >= 2.0 && c1 >= 2.0) tw += d;
    }
    out[2] = (float)(0.1 * tw);
    out[3] = (float)(dzx + exp(-dzs) + exp(-dxs1) + exp(-dxs2));
    double recon = 0.5 * (bce[0] + bce[2]) / (n * 126.0)
                 + 0.5 * (bce[1] + bce[3]) / (n * 2.0);
    out[4] = (float)recon;
    out[5] = (float)(0.5 * (bce[4] + bce[5]) / (n * 128.0));
}

// ===========================================================================
extern "C" void kernel_launch(void* const* d_in, const int* in_sizes, int n_in,
                              void* d_out, int out_size, void* d_ws, size_t ws_size,
                              hipStream_t stream)
{
    const float* x   = (const float*)d_in[0];
    const float* a   = (const float*)d_in[1];
    const float* eps = (const float*)d_in[2];
    const int*   y   = (const int*)d_in[3];
    const float* W1  = (const float*)d_in[4];
    const float* b1  = (const float*)d_in[5];
    const float* g1  = (const float*)d_in[6];
    const float* be1 = (const float*)d_in[7];
    const float* g2  = (const float*)d_in[8];
    const float* be2 = (const float*)d_in[9];
    const float* W2  = (const float*)d_in[10];
    const float* b2  = (const float*)d_in[11];
    const float* Wc1 = (const float*)d_in[12];
    const float* bc1 = (const float*)d_in[13];
    const float* Wc2 = (const float*)d_in[14];
    const float* bc2 = (const float*)d_in[15];
    const float* Wd1 = (const float*)d_in[16];
    const float* bd1 = (const float*)d_in[17];
    const float* Wd2 = (const float*)d_in[18];
    const float* bd2 = (const float*)d_in[19];
    const float* Wn  = (const float*)d_in[20];
    const float* bnb = (const float*)d_in[21];

    char* ws = (char*)d_ws;
    double* st  = (double*)(ws + OFF_STATS);
    float* P    = (float*)(ws + OFF_PAR);
    float* bufA = (float*)(ws + OFF_BUFA);   // U1, later H1o2
    float* bufB = (float*)(ws + OFF_BUFB);   // U2, later H1c2 (in place)
    float* E1   = (float*)(ws + OFF_E1);
    float* E2   = (float*)(ws + OFF_E2);
    float* zx1  = (float*)(ws + OFF_ZX1);
    float* zs1  = (float*)(ws + OFF_ZS1);
    float* zx2  = (float*)(ws + OFF_ZX2);
    float* zs2  = (float*)(ws + OFF_ZS2);
    float* yp   = (float*)(ws + OFF_YP);
    const size_t NS = (size_t)N_ * 10;

    hipMemsetAsync(st, 0, 32768, stream);

    // ---- pass 1 ----
    gemm_plain_kernel<<<N_ / 128, 256, 0, stream>>>(x, DX_, W1, bufA);  // U1
    gemm_plain_kernel<<<N_ / 128, 256, 0, stream>>>(x, DX_, Wn, bufB);  // U2
    stats_p1_bn1_kernel<<<1024, 256, 0, stream>>>(bufA, a, W1, b1, st + ST_P1BN1);
    finalize_bn_kernel<<<2, 128, 0, stream>>>(st + ST_P1BN1, g1, be1, P + PP1BN1);
    stats_p1_bn2_kernel<<<1024, 256, 0, stream>>>(bufA, a, W1, b1, P + PP1BN1, st + ST_P1BN2);
    finalize_bn_kernel<<<2, 128, 0, stream>>>(st + ST_P1BN2, g2, be2, P + PP1BN2);
    tail_p1_kernel<<<N_ / 64, 256, 0, stream>>>(bufA, a, 0, W1, b1,
        P + PP1BN1, P + PP1BN1 + 128, P + PP1BN2, P + PP1BN2 + 128,
        W2, b2, eps + 0 * NS, zx1);
    tail_p1_kernel<<<N_ / 64, 256, 0, stream>>>(bufA, a, 1, W1, b1,
        P + PP1BN1 + 256, P + PP1BN1 + 384, P + PP1BN2 + 256, P + PP1BN2 + 384,
        W2, b2, eps + 2 * NS, zx2);
    cla_argmax_kernel<<<N_ / 256, 256, 0, stream>>>(zx1, zx2, Wc1, bc1, Wc2, bc2, yp);

    // ---- pass 2 ----
    gemm_front_kernel<<<N_ / 128, 256, 0, stream>>>(bufB, a, yp, Wn, bnb, 0, W1, b1, bufA);
    gemm_front_kernel<<<N_ / 128, 256, 0, stream>>>(bufB, a, yp, Wn, bnb, 1, W1, b1, bufB);
    stats_p2_bn1_kernel<<<1024, 256, 0, stream>>>(bufA, bufB, st + ST_P2BN1);
    finalize_bn_kernel<<<2, 128, 0, stream>>>(st + ST_P2BN1, g1, be1, P + PP2BN1);
    stats_p2_bn2_kernel<<<1024, 256, 0, stream>>>(bufA, bufB, P + PP2BN1, st + ST_P2BN2);
    finalize_bn_kernel<<<2, 128, 0, stream>>>(st + ST_P2BN2, g2, be2, P + PP2BN2);
    tail_p2_kernel<<<N_ / 64, 256, 0, stream>>>(bufA,
        P + PP2BN1, P + PP2BN1 + 128, P + PP2BN2, P + PP2BN2 + 128, W2, b2, E1);
    tail_p2_kernel<<<N_ / 64, 256, 0, stream>>>(bufB,
        P + PP2BN1 + 256, P + PP2BN1 + 384, P + PP2BN2 + 256, P + PP2BN2 + 384, W2, b2, E2);
    latents_kernel<<<N_ / 256, 256, 0, stream>>>(E1, E2, eps, y, a,
        Wc1, bc1, Wc2, bc2, zx1, zs1, zx2, zs2, st);
    dec_bce_kernel<<<N_ / DB_ROWS, 256, 0, stream>>>(zx1, zs1, zx2, zs2, x, a,
        Wd1, bd1, Wd2, bd2, st);
    finalize_out_kernel<<<1, 64, 0, stream>>>(st, (float*)d_out);
}

// Round 7
// 2612.759 us; speedup vs baseline: 1.2525x; 1.0543x over previous
//
#include <hip/hip_runtime.h>
#include <hip/hip_bf16.h>
#include <math.h>

// ---------------------------------------------------------------------------
// FairRep forward on MI355X. fp32 throughout (no fp32 MFMA on CDNA4).
// R5 changes vs R4 (2754 us; 4 GEMMs = 1.9 ms, memory-stalled, 5x overfetch):
//  - gemm_dual: U1 & U2 in one kernel (x read once) + pass-1 BN1 stats epilogue
//  - gemm_front_dual: both branches in one kernel (U2 read once, W1 staged
//    once) + pass-2 BN1 stats epilogue; H1c written in place over U2
//  - stats_p1_bn1 / stats_p2_bn1 kernels removed (absorbed)
// ---------------------------------------------------------------------------

#define N_      262144
#define DX_     126

// ---- workspace layout (bytes) ----
static const size_t OFF_STATS = 0;                      // 4096 doubles (32 KB)
static const size_t OFF_PAR   = 32768;                  // 4096 floats (16 KB)
static const size_t OFF_BUFA  = 65536;                  // N*128 f32 (U1 / H1o2)
static const size_t SZ_NH     = (size_t)N_ * 128 * 4;
static const size_t OFF_BUFB  = OFF_BUFA + SZ_NH;       // N*128 f32 (U2 / H1c2)
static const size_t OFF_E1    = OFF_BUFB + SZ_NH;       // N*40
static const size_t OFF_E2    = OFF_E1 + (size_t)N_*40*4;
static const size_t OFF_ZX1   = OFF_E2 + (size_t)N_*40*4;
static const size_t OFF_ZS1   = OFF_ZX1 + (size_t)N_*10*4;
static const size_t OFF_ZX2   = OFF_ZS1 + (size_t)N_*10*4;
static const size_t OFF_ZS2   = OFF_ZX2 + (size_t)N_*10*4;
static const size_t OFF_YP    = OFF_ZS2 + (size_t)N_*10*4;

// ---- stats region (double indices) ----
#define ST_P1BN1    0     // [o: sum 0..127, sumsq 128..255][c: 256..511]
#define ST_P1BN2    512
#define ST_P2BN1    1024
#define ST_P2BN2    1536
#define ST_KLD      2048  // dzx, dzs, dxs1, dxs2
#define ST_CL       2052  // Scl, Scl2, Sxcl, Sx
#define ST_TWIN_CNT 2056  // 4
#define ST_TWIN_S1  2060  // 40
#define ST_TWIN_S2  2100  // 40
#define ST_BCE_PART 2176  // 6 x 64 bins

// ---- bn param region (float indices): [A(128) B(128)] per branch ----
#define PP1BN1  0
#define PP1BN2  512
#define PP2BN1  1024
#define PP2BN2  1536

__device__ __forceinline__ float softplus_f(float u) {
    return fmaxf(u, 0.0f) + __logf(1.0f + __expf(-fabsf(u)));
}
__device__ __forceinline__ float sigmoid_f(float u) {
    return __builtin_amdgcn_rcpf(1.0f + __expf(-u));
}

#define BKg 32

// per-thread 4-col stat vector -> LDS tree over 8 row-groups -> global double
#define REDUCE_STAT(vec, off)                                        \
    __syncthreads();                                                 \
    _Pragma("unroll")                                                \
    for (int j = 0; j < 4; ++j) red[rg][tc + j] = vec[j];            \
    __syncthreads();                                                 \
    if (tid < 128) {                                                 \
        float tsum = 0.0f;                                           \
        _Pragma("unroll")                                            \
        for (int g = 0; g < 8; ++g) tsum += red[g][tid];             \
        atomicAdd(&stat[(off) + tid], (double)tsum);                 \
    }

// ===========================================================================
// gemm_dual: C1 = x@W1[:126], C2 = x@Wn[:126]; epilogue computes pass-1 BN1
// stats (h_o = C1 + a0*w6 + a1*w7 + b1; h_c with 1-a).
// BM=64, BK=32, 256 threads, dual 8x4 micro-tile. grid N/64.
// ===========================================================================
__global__ __launch_bounds__(256, 3) void gemm_dual_kernel(
    const float* __restrict__ A, const float* __restrict__ W1,
    const float* __restrict__ Wn, const float* __restrict__ a,
    const float* __restrict__ b1,
    float* __restrict__ C1, float* __restrict__ C2,
    double* __restrict__ stat)
{
    __shared__ __align__(16) float As[BKg][68];
    __shared__ __align__(16) float B1s[BKg][128];
    __shared__ __align__(16) float B2s[BKg][128];
    __shared__ float red[8][128];
    const int row0 = blockIdx.x * 64;
    const int tid  = threadIdx.x;
    const int tr   = (tid >> 5) * 8;    // 0..56
    const int tc   = (tid & 31) * 4;    // 0..124
    const int rg   = tid >> 5;
    float acc1[8][4] = {}, acc2[8][4] = {};
    for (int kc = 0; kc < 4; ++kc) {
        const int k0 = kc * 32;
        #pragma unroll
        for (int i = 0; i < 8; ++i) {
            int idx = tid + i * 256;
            int m = idx >> 5, k = idx & 31;
            int gk = k0 + k;
            As[k][m] = (gk < DX_) ? A[(size_t)(row0 + m) * DX_ + gk] : 0.0f;
        }
        #pragma unroll
        for (int i = 0; i < 16; ++i) {
            int idx = tid + i * 256;
            int k = idx >> 7, n = idx & 127;
            int gk = k0 + k;
            B1s[k][n] = (gk < DX_) ? W1[(size_t)gk * 128 + n] : 0.0f;
            B2s[k][n] = (gk < DX_) ? Wn[(size_t)gk * 128 + n] : 0.0f;
        }
        __syncthreads();
        #pragma unroll
        for (int k = 0; k < BKg; ++k) {
            float4 av0 = *(const float4*)&As[k][tr];
            float4 av1 = *(const float4*)&As[k][tr + 4];
            float4 bv1 = *(const float4*)&B1s[k][tc];
            float4 bv2 = *(const float4*)&B2s[k][tc];
            float av[8] = {av0.x, av0.y, av0.z, av0.w, av1.x, av1.y, av1.z, av1.w};
            float w1v[4] = {bv1.x, bv1.y, bv1.z, bv1.w};
            float w2v[4] = {bv2.x, bv2.y, bv2.z, bv2.w};
            #pragma unroll
            for (int i = 0; i < 8; ++i)
                #pragma unroll
                for (int j = 0; j < 4; ++j) {
                    acc1[i][j] = fmaf(av[i], w1v[j], acc1[i][j]);
                    acc2[i][j] = fmaf(av[i], w2v[j], acc2[i][j]);
                }
        }
        __syncthreads();
    }
    // ---- write U1, U2 ----
    #pragma unroll
    for (int i = 0; i < 8; ++i) {
        size_t base = (size_t)(row0 + tr + i) * 128 + tc;
        float4 v1 = {acc1[i][0], acc1[i][1], acc1[i][2], acc1[i][3]};
        float4 v2 = {acc2[i][0], acc2[i][1], acc2[i][2], acc2[i][3]};
        *(float4*)&C1[base] = v1;
        *(float4*)&C2[base] = v2;
    }
    // ---- pass-1 BN1 stats from registers ----
    float w6[4], w7[4], bb[4];
    #pragma unroll
    for (int j = 0; j < 4; ++j) {
        w6[j] = W1[126 * 128 + tc + j];
        w7[j] = W1[127 * 128 + tc + j];
        bb[j] = b1[tc + j];
    }
    float ra0[8], ra1[8];
    #pragma unroll
    for (int i = 0; i < 8; ++i) {
        ra0[i] = a[2 * (row0 + tr + i)];
        ra1[i] = a[2 * (row0 + tr + i) + 1];
    }
    float s_ho[4] = {}, q_ho[4] = {}, s_hc[4] = {}, q_hc[4] = {};
    #pragma unroll
    for (int i = 0; i < 8; ++i)
        #pragma unroll
        for (int j = 0; j < 4; ++j) {
            float u  = acc1[i][j];
            float ho = u + ra0[i] * w6[j] + ra1[i] * w7[j] + bb[j];
            float hc = u + (1.0f - ra0[i]) * w6[j] + (1.0f - ra1[i]) * w7[j] + bb[j];
            s_ho[j] += ho; q_ho[j] += ho * ho;
            s_hc[j] += hc; q_hc[j] += hc * hc;
        }
    REDUCE_STAT(s_ho, 0)
    REDUCE_STAT(q_ho, 128)
    REDUCE_STAT(s_hc, 256)
    REDUCE_STAT(q_hc, 384)
}

// ===========================================================================
// gemm_front_dual: out_o = relu(U2 + a0*w6 + a1*w7 + yp*w8 + bnb), out_c with
// (1-a); H1o = out_o@W1 + b1, H1c = out_c@W1 + b1 (H1c in place over U2).
// Epilogue computes pass-2 BN1 stats for both branches. grid N/64.
// ===========================================================================
__global__ __launch_bounds__(256, 3) void gemm_front_dual_kernel(
    const float* U2, const float* __restrict__ a,
    const float* __restrict__ ypred, const float* __restrict__ Wn,
    const float* __restrict__ bnb,
    const float* __restrict__ W1, const float* __restrict__ b1,
    float* __restrict__ H1o, float* H1c,
    double* __restrict__ stat)
{
    __shared__ __align__(16) float Ao[BKg][68];
    __shared__ __align__(16) float Ac[BKg][68];
    __shared__ __align__(16) float Bs[BKg][128];
    __shared__ float red[8][128];
    __shared__ float sa0[64], sa1[64], syp[64];
    const int row0 = blockIdx.x * 64;
    const int tid  = threadIdx.x;
    if (tid < 64) {
        int r = row0 + tid;
        sa0[tid] = a[2 * r]; sa1[tid] = a[2 * r + 1]; syp[tid] = ypred[r];
    }
    __syncthreads();
    const int tr = (tid >> 5) * 8;
    const int tc = (tid & 31) * 4;
    const int rg = tid >> 5;
    float acco[8][4] = {}, accc[8][4] = {};
    for (int kc = 0; kc < 4; ++kc) {
        const int k0 = kc * 32;
        #pragma unroll
        for (int i = 0; i < 8; ++i) {
            int idx = tid + i * 256;
            int m = idx >> 5, k = idx & 31;
            int gk = k0 + k;
            float u  = U2[(size_t)(row0 + m) * 128 + gk];
            float w6 = Wn[126 * 128 + gk], w7 = Wn[127 * 128 + gk];
            float w8 = Wn[128 * 128 + gk];
            float vb = u + syp[m] * w8 + bnb[gk];
            float vo = vb + sa0[m] * w6 + sa1[m] * w7;
            float vc = vb + (1.0f - sa0[m]) * w6 + (1.0f - sa1[m]) * w7;
            Ao[k][m] = fmaxf(vo, 0.0f);
            Ac[k][m] = fmaxf(vc, 0.0f);
        }
        #pragma unroll
        for (int i = 0; i < 16; ++i) {
            int idx = tid + i * 256;
            int k = idx >> 7, n = idx & 127;
            Bs[k][n] = W1[(size_t)(k0 + k) * 128 + n];
        }
        __syncthreads();
        #pragma unroll
        for (int k = 0; k < BKg; ++k) {
            float4 ao0 = *(const float4*)&Ao[k][tr];
            float4 ao1 = *(const float4*)&Ao[k][tr + 4];
            float4 ac0 = *(const float4*)&Ac[k][tr];
            float4 ac1 = *(const float4*)&Ac[k][tr + 4];
            float4 bv  = *(const float4*)&Bs[k][tc];
            float aov[8] = {ao0.x, ao0.y, ao0.z, ao0.w, ao1.x, ao1.y, ao1.z, ao1.w};
            float acv[8] = {ac0.x, ac0.y, ac0.z, ac0.w, ac1.x, ac1.y, ac1.z, ac1.w};
            float bvv[4] = {bv.x, bv.y, bv.z, bv.w};
            #pragma unroll
            for (int i = 0; i < 8; ++i)
                #pragma unroll
                for (int j = 0; j < 4; ++j) {
                    acco[i][j] = fmaf(aov[i], bvv[j], acco[i][j]);
                    accc[i][j] = fmaf(acv[i], bvv[j], accc[i][j]);
                }
        }
        __syncthreads();
    }
    // ---- add bias, write H1o/H1c, stats from registers ----
    float bb[4];
    #pragma unroll
    for (int j = 0; j < 4; ++j) bb[j] = b1[tc + j];
    float s_o[4] = {}, q_o[4] = {}, s_c[4] = {}, q_c[4] = {};
    #pragma unroll
    for (int i = 0; i < 8; ++i) {
        float ho[4], hc[4];
        #pragma unroll
        for (int j = 0; j < 4; ++j) {
            ho[j] = acco[i][j] + bb[j];
            hc[j] = accc[i][j] + bb[j];
            s_o[j] += ho[j]; q_o[j] += ho[j] * ho[j];
            s_c[j] += hc[j]; q_c[j] += hc[j] * hc[j];
        }
        size_t base = (size_t)(row0 + tr + i) * 128 + tc;
        float4 vo4 = {ho[0], ho[1], ho[2], ho[3]};
        float4 vc4 = {hc[0], hc[1], hc[2], hc[3]};
        *(float4*)&H1o[base] = vo4;
        *(float4*)&H1c[base] = vc4;
    }
    REDUCE_STAT(s_o, 0)
    REDUCE_STAT(q_o, 128)
    REDUCE_STAT(s_c, 256)
    REDUCE_STAT(q_c, 384)
}

// ===========================================================================
// Pass-1 BN2 stats. grid 1024.
// ===========================================================================
__global__ __launch_bounds__(256) void stats_p1_bn2_kernel(
    const float* __restrict__ U1, const float* __restrict__ a,
    const float* __restrict__ W1, const float* __restrict__ b1,
    const float* __restrict__ Pbn1, double* __restrict__ stat)
{
    const int tid = threadIdx.x;
    const int col = tid & 127, half = tid >> 7;
    const int r0 = blockIdx.x * 256 + half * 128;
    const float w6 = W1[126 * 128 + col], w7 = W1[127 * 128 + col];
    const float bb = b1[col];
    const float A1o = Pbn1[col],       B1o = Pbn1[128 + col];
    const float A1c = Pbn1[256 + col], B1c = Pbn1[384 + col];
    double dso = 0, dqo = 0, dsc = 0, dqc = 0;
    for (int i0 = 0; i0 < 128; i0 += 64) {
        float so = 0, qo = 0, sc = 0, qc = 0;
        for (int i = i0; i < i0 + 64; ++i) {
            int r = r0 + i;
            float u  = U1[(size_t)r * 128 + col];
            float a0 = a[2 * r], a1 = a[2 * r + 1];
            float ho = u + a0 * w6 + a1 * w7 + bb;
            float hc = u + (1.0f - a0) * w6 + (1.0f - a1) * w7 + bb;
            float r1o = fmaxf(fmaf(A1o, ho, B1o), 0.0f);
            float r1c = fmaxf(fmaf(A1c, hc, B1c), 0.0f);
            so += r1o; qo += r1o * r1o; sc += r1c; qc += r1c * r1c;
        }
        dso += so; dqo += qo; dsc += sc; dqc += qc;
    }
    __shared__ double red[4][128];
    if (half == 1) { red[0][col]=dso; red[1][col]=dqo; red[2][col]=dsc; red[3][col]=dqc; }
    __syncthreads();
    if (half == 0) {
        atomicAdd(&stat[col],       dso + red[0][col]);
        atomicAdd(&stat[128 + col], dqo + red[1][col]);
        atomicAdd(&stat[256 + col], dsc + red[2][col]);
        atomicAdd(&stat[384 + col], dqc + red[3][col]);
    }
}

// Pass-2 BN2 stats. grid 1024; thread=(col,branch); 256 rows each.
__global__ __launch_bounds__(256) void stats_p2_bn2_kernel(
    const float* __restrict__ H1o, const float* __restrict__ H1c,
    const float* __restrict__ Pbn1, double* __restrict__ stat)
{
    const int tid = threadIdx.x;
    const int col = tid & 127, br = tid >> 7;
    const float* H = br ? H1c : H1o;
    const float A1 = Pbn1[br * 256 + col], B1 = Pbn1[br * 256 + 128 + col];
    const int r0 = blockIdx.x * 256;
    double ds = 0, dq = 0;
    for (int i0 = 0; i0 < 256; i0 += 64) {
        float s = 0, q = 0;
        for (int i = i0; i < i0 + 64; ++i) {
            float h = H[(size_t)(r0 + i) * 128 + col];
            float r1 = fmaxf(fmaf(A1, h, B1), 0.0f);
            s += r1; q += r1 * r1;
        }
        ds += s; dq += q;
    }
    atomicAdd(&stat[br * 256 + col], ds);
    atomicAdd(&stat[br * 256 + 128 + col], dq);
}

// grid 2 (branch), 128 threads: mu/var -> scale A, shift B
__global__ void finalize_bn_kernel(const double* __restrict__ stat,
                                   const float* __restrict__ g,
                                   const float* __restrict__ be,
                                   float* __restrict__ Pout)
{
    const int br = blockIdx.x, j = threadIdx.x;
    double s = stat[br * 256 + j], q = stat[br * 256 + 128 + j];
    double mu = s / (double)N_;
    double var = q / (double)N_ - mu * mu;
    float rstd = (float)rsqrt(var + 1e-5);
    float A = g[j] * rstd;
    float B = be[j] - (float)mu * A;
    Pout[br * 256 + j] = A;
    Pout[br * 256 + 128 + j] = B;
}

// ===========================================================================
// Pass-1 tail. 64 rows/block, 256 threads.
// ===========================================================================
__global__ __launch_bounds__(256) void tail_p1_kernel(
    const float* __restrict__ U1, const float* __restrict__ a, int conj,
    const float* __restrict__ W1, const float* __restrict__ b1,
    const float* __restrict__ A1p, const float* __restrict__ B1p,
    const float* __restrict__ A2p, const float* __restrict__ B2p,
    const float* __restrict__ W2, const float* __restrict__ b2,
    const float* __restrict__ epsk, float* __restrict__ zout)
{
    __shared__ float As[128][69];
    __shared__ float outs[64][24];
    const int row0 = blockIdx.x * 64;
    const int tid  = threadIdx.x;
    for (int i = tid; i < 64 * 128; i += 256) {
        int r = i >> 7, k = i & 127;
        int gr = row0 + r;
        float a0 = a[2 * gr], a1 = a[2 * gr + 1];
        if (conj) { a0 = 1.0f - a0; a1 = 1.0f - a1; }
        float h = U1[(size_t)gr * 128 + k] + a0 * W1[126 * 128 + k]
                + a1 * W1[127 * 128 + k] + b1[k];
        float r1 = fmaxf(fmaf(A1p[k], h, B1p[k]), 0.0f);
        float r2 = fmaxf(fmaf(A2p[k], r1, B2p[k]), 0.0f);
        As[k][r] = r2;
    }
    __syncthreads();
    const int row = tid & 63;
    const int cg  = tid >> 6;
    const int wbase = __builtin_amdgcn_readfirstlane((cg < 2) ? cg * 5 : 10 + cg * 5);
    float acc[5] = {};
    for (int k = 0; k < 128; ++k) {
        float av = As[k][row];
        #pragma unroll
        for (int c = 0; c < 5; ++c)
            acc[c] = fmaf(av, W2[k * 40 + wbase + c], acc[c]);
    }
    #pragma unroll
    for (int c = 0; c < 5; ++c)
        outs[row][cg * 5 + c] = acc[c] + b2[wbase + c];
    __syncthreads();
    if (tid < 128) {
        int r = tid & 63, dg = tid >> 6;
        int gr = row0 + r;
        #pragma unroll
        for (int c = 0; c < 5; ++c) {
            int d = dg * 5 + c;
            float mx = outs[r][d], lx = outs[r][10 + d];
            zout[(size_t)gr * 10 + d] =
                epsk[(size_t)gr * 10 + d] * __expf(0.5f * lx) + mx;
        }
    }
}

// Pass-2 tail: full 40-col output E = r2@W2 + b2.
__global__ __launch_bounds__(256) void tail_p2_kernel(
    const float* __restrict__ H1,
    const float* __restrict__ A1p, const float* __restrict__ B1p,
    const float* __restrict__ A2p, const float* __restrict__ B2p,
    const float* __restrict__ W2, const float* __restrict__ b2,
    float* __restrict__ E)
{
    __shared__ float As[128][69];
    __shared__ float outs[64][44];
    const int row0 = blockIdx.x * 64;
    const int tid  = threadIdx.x;
    for (int i = tid; i < 64 * 128; i += 256) {
        int r = i >> 7, k = i & 127;
        float h = H1[(size_t)(row0 + r) * 128 + k];
        float r1 = fmaxf(fmaf(A1p[k], h, B1p[k]), 0.0f);
        float r2 = fmaxf(fmaf(A2p[k], r1, B2p[k]), 0.0f);
        As[k][r] = r2;
    }
    __syncthreads();
    const int row = tid & 63;
    const int cg  = tid >> 6;
    const int wbase = __builtin_amdgcn_readfirstlane(cg * 10);
    float acc[10] = {};
    for (int k = 0; k < 128; ++k) {
        float av = As[k][row];
        #pragma unroll
        for (int c = 0; c < 10; ++c)
            acc[c] = fmaf(av, W2[k * 40 + wbase + c], acc[c]);
    }
    #pragma unroll
    for (int c = 0; c < 10; ++c)
        outs[row][wbase + c] = acc[c] + b2[wbase + c];
    __syncthreads();
    size_t base = (size_t)row0 * 40;
    for (int i = tid; i < 64 * 40; i += 256)
        E[base + i] = outs[i / 40][i % 40];
}

// ===========================================================================
// cla(zx1)+cla(zx2) argmax -> y_pred (float 0/1)
// ===========================================================================
__global__ __launch_bounds__(256) void cla_argmax_kernel(
    const float* __restrict__ zx1, const float* __restrict__ zx2,
    const float* __restrict__ Wc1, const float* __restrict__ bc1,
    const float* __restrict__ Wc2, const float* __restrict__ bc2,
    float* __restrict__ ypred)
{
    const int r = blockIdx.x * 256 + threadIdx.x;
    float z1[10], z2[10];
    #pragma unroll
    for (int d = 0; d < 10; ++d) {
        z1[d] = zx1[(size_t)r * 10 + d];
        z2[d] = zx2[(size_t)r * 10 + d];
    }
    float lg0 = 2.0f * bc2[0], lg1 = 2.0f * bc2[1];
    #pragma unroll
    for (int j = 0; j < 32; ++j) {
        float s1 = bc1[j], s2 = bc1[j];
        #pragma unroll
        for (int d = 0; d < 10; ++d) {
            float w = Wc1[d * 32 + j];
            s1 += z1[d] * w; s2 += z2[d] * w;
        }
        float s = s1 + s2;
        lg0 += s * Wc2[j * 2 + 0];
        lg1 += s * Wc2[j * 2 + 1];
    }
    ypred[r] = (lg1 > lg0) ? 1.0f : 0.0f;
}

// ===========================================================================
// latents: KLDs, z samples, cl (ce+moments), twin group stats.
// ===========================================================================
__device__ __forceinline__ float sym10(const float* m1, const float* l1,
                                       const float* m2, const float* l2)
{
    float t12 = 0, t21 = 0;
    #pragma unroll
    for (int j = 0; j < 10; ++j) {
        float dl = l1[j] - l2[j];
        float md = m1[j] - m2[j]; md *= md;
        t12 += -dl + __expf(dl)  + md * __expf(-l2[j]);
        t21 +=  dl + __expf(-dl) + md * __expf(-l1[j]);
    }
    return 0.025f * ((t12 - 10.0f) + (t21 - 10.0f));
}

__device__ __forceinline__ float ce2_of(const float* z, int yv,
    const float* Wc1, const float* bc1, const float* Wc2, const float* bc2)
{
    float lg0 = bc2[0], lg1 = bc2[1];
    #pragma unroll
    for (int j = 0; j < 32; ++j) {
        float s = bc1[j];
        #pragma unroll
        for (int d = 0; d < 10; ++d) s += z[d] * Wc1[d * 32 + j];
        lg0 += s * Wc2[j * 2 + 0];
        lg1 += s * Wc2[j * 2 + 1];
    }
    float m = fmaxf(lg0, lg1);
    float lse = m + __logf(__expf(lg0 - m) + __expf(lg1 - m));
    float ly = yv ? lg1 : lg0;
    return -(ly - lse);
}

__global__ __launch_bounds__(256) void latents_kernel(
    const float* __restrict__ E1, const float* __restrict__ E2,
    const float* __restrict__ eps,
    const int* __restrict__ y, const float* __restrict__ a,
    const float* __restrict__ Wc1, const float* __restrict__ bc1,
    const float* __restrict__ Wc2, const float* __restrict__ bc2,
    float* __restrict__ zx1, float* __restrict__ zs1,
    float* __restrict__ zx2, float* __restrict__ zs2,
    double* __restrict__ stat)
{
    __shared__ float tw_cnt[4], tw_s1[40], tw_s2[40];
    __shared__ float redw[4][8];
    const int tid = threadIdx.x;
    if (tid < 4) tw_cnt[tid] = 0.0f;
    if (tid < 40) { tw_s1[tid] = 0.0f; tw_s2[tid] = 0.0f; }
    __syncthreads();

    const int r = blockIdx.x * 256 + tid;
    const size_t NS = (size_t)N_ * 10;
    float e1[40], e2[40];
    #pragma unroll
    for (int i = 0; i < 40; ++i) {
        e1[i] = E1[(size_t)r * 40 + i];
        e2[i] = E2[(size_t)r * 40 + i];
    }
    float s_dzx  = sym10(e1 + 0,  e1 + 20, e2 + 0,  e2 + 20);
    float s_dzs  = sym10(e1 + 10, e1 + 30, e2 + 10, e2 + 30);
    float s_dxs1 = sym10(e1 + 0,  e1 + 20, e1 + 10, e1 + 30);
    float s_dxs2 = sym10(e2 + 0,  e2 + 20, e2 + 10, e2 + 30);

    float z1[10], z2[10];
    #pragma unroll
    for (int d = 0; d < 10; ++d) {
        size_t rd = (size_t)r * 10 + d;
        float v1 = eps[4 * NS + rd] * __expf(0.5f * e1[20 + d]) + e1[d];
        float t1 = eps[5 * NS + rd] * __expf(0.5f * e1[30 + d]) + e1[10 + d];
        float v2 = eps[6 * NS + rd] * __expf(0.5f * e2[20 + d]) + e2[d];
        float t2 = eps[7 * NS + rd] * __expf(0.5f * e2[30 + d]) + e2[10 + d];
        zx1[rd] = v1; zs1[rd] = t1; zx2[rd] = v2; zs2[rd] = t2;
        z1[d] = v1; z2[d] = v2;
    }

    const int yv = y[r];
    float ce1 = ce2_of(z1, yv, Wc1, bc1, Wc2, bc2);
    float ce2 = ce2_of(z2, yv, Wc1, bc1, Wc2, bc2);
    float cl = 0.5f * (ce1 + ce2);
    float atag = (a[2 * r + 1] > a[2 * r]) ? 1.0f : 0.0f;

    int gid = yv * 2 + (int)atag;
    atomicAdd(&tw_cnt[gid], 1.0f);
    #pragma unroll
    for (int d = 0; d < 10; ++d) {
        atomicAdd(&tw_s1[gid * 10 + d], z1[d]);
        atomicAdd(&tw_s2[gid * 10 + d], z1[d] * z1[d]);
    }

    float vals[8] = {s_dzx, s_dzs, s_dxs1, s_dxs2, cl, cl * cl, atag * cl, atag};
    #pragma unroll
    for (int v = 0; v < 8; ++v) {
        float sv = vals[v];
        #pragma unroll
        for (int off = 1; off < 64; off <<= 1) sv += __shfl_xor(sv, off);
        vals[v] = sv;
    }
    const int wave = tid >> 6;
    if ((tid & 63) == 0) {
        #pragma unroll
        for (int v = 0; v < 8; ++v) redw[wave][v] = vals[v];
    }
    __syncthreads();
    if (tid < 8) {
        float s = redw[0][tid] + redw[1][tid] + redw[2][tid] + redw[3][tid];
        atomicAdd(&stat[ST_KLD + tid], (double)s);
    }
    if (tid < 4)  atomicAdd(&stat[ST_TWIN_CNT + tid], (double)tw_cnt[tid]);
    if (tid < 40) {
        atomicAdd(&stat[ST_TWIN_S1 + tid], (double)tw_s1[tid]);
        atomicAdd(&stat[ST_TWIN_S2 + tid], (double)tw_s2[tid]);
    }
}

// ===========================================================================
// Decoder + BCE. 32 rows/block, 8 threads per row, LDS-staged h + Wd2.
// ===========================================================================
#define DB_ROWS 32

__global__ __launch_bounds__(256) void dec_bce_kernel(
    const float* __restrict__ zx1, const float* __restrict__ zs1,
    const float* __restrict__ zx2, const float* __restrict__ zs2,
    const float* __restrict__ x, const float* __restrict__ a,
    const float* __restrict__ Wd1, const float* __restrict__ bd1,
    const float* __restrict__ Wd2, const float* __restrict__ bd2,
    double* __restrict__ stat)
{
    __shared__ float zsh[DB_ROWS][40];
    __shared__ float hsh[DB_ROWS][68];
    __shared__ float wsh[16 * 128];
    __shared__ float bsh[128];
    __shared__ float ash[DB_ROWS][2];
    __shared__ float redw[4][8];
    const int t = threadIdx.x;
    const int row0 = blockIdx.x * DB_ROWS;

    for (int i = t; i < DB_ROWS * 40; i += 256) {
        int rr = i / 40, d = i % 40;
        const float* src = (d < 10) ? zx1 : (d < 20) ? zs1 : (d < 30) ? zx2 : zs2;
        zsh[rr][d] = src[(size_t)(row0 + rr) * 10 + (d % 10)];
    }
    for (int i = t; i < 2048; i += 256) wsh[i] = Wd2[i];
    if (t < 128) bsh[t] = bd2[t];
    if (t < 64) { int rr = t >> 1, c = t & 1; ash[rr][c] = a[2 * (row0 + rr) + c]; }
    __syncthreads();

    for (int i = t; i < DB_ROWS * 64; i += 256) {
        int rr = i >> 6, ck = i & 63, c = ck >> 4, k = ck & 15;
        int oA = (c == 0 || c == 2) ? 0 : 20;
        int oB = (c == 0 || c == 3) ? 10 : 30;
        float s = bd1[k];
        #pragma unroll
        for (int d = 0; d < 10; ++d) {
            s = fmaf(zsh[rr][oA + d], Wd1[d * 16 + k], s);
            s = fmaf(zsh[rr][oB + d], Wd1[(10 + d) * 16 + k], s);
        }
        hsh[rr][c * 16 + k] = s;
    }
    __syncthreads();

    const int rloc = t >> 3, jl = t & 7;
    const int gr = row0 + rloc;
    float h0[16], h1[16], h2[16], h3[16];
    #pragma unroll
    for (int k = 0; k < 16; ++k) {
        h0[k] = hsh[rloc][k];      h1[k] = hsh[rloc][16 + k];
        h2[k] = hsh[rloc][32 + k]; h3[k] = hsh[rloc][48 + k];
    }
    const float a0 = ash[rloc][0], a1 = ash[rloc][1];
    float s1x = 0, s1a = 0, s2x = 0, s2a = 0, ss1 = 0, ss2 = 0;
    #pragma unroll 4
    for (int i = 0; i < 16; ++i) {
        const int j = jl + 8 * i;
        float u0 = bsh[j], u1 = bsh[j], u2 = bsh[j], u3 = bsh[j];
        #pragma unroll
        for (int k = 0; k < 16; ++k) {
            float w = wsh[k * 128 + j];
            u0 = fmaf(h0[k], w, u0); u1 = fmaf(h1[k], w, u1);
            u2 = fmaf(h2[k], w, u2); u3 = fmaf(h3[k], w, u3);
        }
        float sp0 = softplus_f(u0), sp1 = softplus_f(u1);
        float sp2 = softplus_f(u2), sp3 = softplus_f(u3);
        if (j < 126) {
            float tt = sigmoid_f(x[(size_t)gr * 126 + j]);
            s1x += sp0 - tt * u0; s2x += sp1 - tt * u1;
            ss1 += sp2 - tt * u2; ss2 += sp3 - tt * u3;
        } else {
            float av = (j == 126) ? a0 : a1;
            float tt = sigmoid_f(av);
            s1a += sp0 - tt * u0; s2a += sp1 - tt * u1;
            ss1 += sp2 - tt * u2;
            float t2 = sigmoid_f(1.0f - av);
            ss2 += sp3 - t2 * u3;
        }
    }

    float vals[6] = {s1x, s1a, s2x, s2a, ss1, ss2};
    #pragma unroll
    for (int v = 0; v < 6; ++v) {
        float sv = vals[v];
        #pragma unroll
        for (int off = 1; off < 64; off <<= 1) sv += __shfl_xor(sv, off);
        vals[v] = sv;
    }
    const int wave = t >> 6;
    if ((t & 63) == 0) {
        #pragma unroll
        for (int v = 0; v < 6; ++v) redw[wave][v] = vals[v];
    }
    __syncthreads();
    if (t < 6) {
        float s = redw[0][t] + redw[1][t] + redw[2][t] + redw[3][t];
        atomicAdd(&stat[ST_BCE_PART + t * 64 + (blockIdx.x & 63)], (double)s);
    }
}

// ===========================================================================
// Final scalar assembly.
// ===========================================================================
__global__ void finalize_out_kernel(const double* __restrict__ st,
                                    float* __restrict__ out)
{
    if (threadIdx.x != 0 || blockIdx.x != 0) return;
    const double n = (double)N_;
    double bce[6];
    for (int v = 0; v < 6; ++v) {
        double s = 0;
        for (int b = 0; b < 64; ++b) s += st[ST_BCE_PART + v * 64 + b];
        bce[v] = s;
    }
    double dzx  = st[ST_KLD + 0] / n, dzs  = st[ST_KLD + 1] / n;
    double dxs1 = st[ST_KLD + 2] / n, dxs2 = st[ST_KLD + 3] / n;
    double Scl = st[ST_CL + 0], Scl2 = st[ST_CL + 1];
    double Sxcl = st[ST_CL + 2], Sx = st[ST_CL + 3];
    out[0] = (float)Scl;
    double xm = Sx / n, ym = Scl / n;
    double xv = (Sx - n * xm * xm) / (n - 1.0);
    double yv = (Scl2 - n * ym * ym) / (n - 1.0);
    double c  = fabs((Sxcl - n * xm * ym) / sqrt(xv * yv));
    out[1] = (float)((xm == 0.0) ? 0.0 : c);
    double tw = 0.0;
    for (int yy = 0; yy < 2; ++yy) {
        double c0 = st[ST_TWIN_CNT + yy * 2], c1 = st[ST_TWIN_CNT + yy * 2 + 1];
        double d = 0.0;
        for (int j = 0; j < 10; ++j) {
            double m0 = st[ST_TWIN_S1 + (yy * 2) * 10 + j]     / fmax(c0, 1.0);
            double m1 = st[ST_TWIN_S1 + (yy * 2 + 1) * 10 + j] / fmax(c1, 1.0);
            double w0 = (st[ST_TWIN_S2 + (yy * 2) * 10 + j]     - c0 * m0 * m0) / fmax(c0 - 1.0, 1.0);
            double w1 = (st[ST_TWIN_S2 + (yy * 2 + 1) * 10 + j] - c1 * m1 * m1) / fmax(c1 - 1.0, 1.0);
            d += (m0 - m1) * (m0 - m1) + (w0 - w1) * (w0 - w1);
        }
        if (c0 >= 2.0 && c1 >= 2.0) tw += d;
    }
    out[2] = (float)(0.1 * tw);
    out[3] = (float)(dzx + exp(-dzs) + exp(-dxs1) + exp(-dxs2));
    double recon = 0.5 * (bce[0] + bce[2]) / (n * 126.0)
                 + 0.5 * (bce[1] + bce[3]) / (n * 2.0);
    out[4] = (float)recon;
    out[5] = (float)(0.5 * (bce[4] + bce[5]) / (n * 128.0));
}

// ===========================================================================
extern "C" void kernel_launch(void* const* d_in, const int* in_sizes, int n_in,
                              void* d_out, int out_size, void* d_ws, size_t ws_size,
                              hipStream_t stream)
{
    const float* x   = (const float*)d_in[0];
    const float* a   = (const float*)d_in[1];
    const float* eps = (const float*)d_in[2];
    const int*   y   = (const int*)d_in[3];
    const float* W1  = (const float*)d_in[4];
    const float* b1  = (const float*)d_in[5];
    const float* g1  = (const float*)d_in[6];
    const float* be1 = (const float*)d_in[7];
    const float* g2  = (const float*)d_in[8];
    const float* be2 = (const float*)d_in[9];
    const float* W2  = (const float*)d_in[10];
    const float* b2  = (const float*)d_in[11];
    const float* Wc1 = (const float*)d_in[12];
    const float* bc1 = (const float*)d_in[13];
    const float* Wc2 = (const float*)d_in[14];
    const float* bc2 = (const float*)d_in[15];
    const float* Wd1 = (const float*)d_in[16];
    const float* bd1 = (const float*)d_in[17];
    const float* Wd2 = (const float*)d_in[18];
    const float* bd2 = (const float*)d_in[19];
    const float* Wn  = (const float*)d_in[20];
    const float* bnb = (const float*)d_in[21];

    char* ws = (char*)d_ws;
    double* st  = (double*)(ws + OFF_STATS);
    float* P    = (float*)(ws + OFF_PAR);
    float* bufA = (float*)(ws + OFF_BUFA);   // U1, later H1o2
    float* bufB = (float*)(ws + OFF_BUFB);   // U2, later H1c2 (in place)
    float* E1   = (float*)(ws + OFF_E1);
    float* E2   = (float*)(ws + OFF_E2);
    float* zx1  = (float*)(ws + OFF_ZX1);
    float* zs1  = (float*)(ws + OFF_ZS1);
    float* zx2  = (float*)(ws + OFF_ZX2);
    float* zs2  = (float*)(ws + OFF_ZS2);
    float* yp   = (float*)(ws + OFF_YP);
    const size_t NS = (size_t)N_ * 10;

    hipMemsetAsync(st, 0, 32768, stream);

    // ---- pass 1 ----
    gemm_dual_kernel<<<N_ / 64, 256, 0, stream>>>(x, W1, Wn, a, b1,
        bufA, bufB, st + ST_P1BN1);
    finalize_bn_kernel<<<2, 128, 0, stream>>>(st + ST_P1BN1, g1, be1, P + PP1BN1);
    stats_p1_bn2_kernel<<<1024, 256, 0, stream>>>(bufA, a, W1, b1, P + PP1BN1, st + ST_P1BN2);
    finalize_bn_kernel<<<2, 128, 0, stream>>>(st + ST_P1BN2, g2, be2, P + PP1BN2);
    tail_p1_kernel<<<N_ / 64, 256, 0, stream>>>(bufA, a, 0, W1, b1,
        P + PP1BN1, P + PP1BN1 + 128, P + PP1BN2, P + PP1BN2 + 128,
        W2, b2, eps + 0 * NS, zx1);
    tail_p1_kernel<<<N_ / 64, 256, 0, stream>>>(bufA, a, 1, W1, b1,
        P + PP1BN1 + 256, P + PP1BN1 + 384, P + PP1BN2 + 256, P + PP1BN2 + 384,
        W2, b2, eps + 2 * NS, zx2);
    cla_argmax_kernel<<<N_ / 256, 256, 0, stream>>>(zx1, zx2, Wc1, bc1, Wc2, bc2, yp);

    // ---- pass 2 ----
    gemm_front_dual_kernel<<<N_ / 64, 256, 0, stream>>>(bufB, a, yp, Wn, bnb,
        W1, b1, bufA, bufB, st + ST_P2BN1);
    finalize_bn_kernel<<<2, 128, 0, stream>>>(st + ST_P2BN1, g1, be1, P + PP2BN1);
    stats_p2_bn2_kernel<<<1024, 256, 0, stream>>>(bufA, bufB, P + PP2BN1, st + ST_P2BN2);
    finalize_bn_kernel<<<2, 128, 0, stream>>>(st + ST_P2BN2, g2, be2, P + PP2BN2);
    tail_p2_kernel<<<N_ / 64, 256, 0, stream>>>(bufA,
        P + PP2BN1, P + PP2BN1 + 128, P + PP2BN2, P + PP2BN2 + 128, W2, b2, E1);
    tail_p2_kernel<<<N_ / 64, 256, 0, stream>>>(bufB,
        P + PP2BN1 + 256, P + PP2BN1 + 384, P + PP2BN2 + 256, P + PP2BN2 + 384, W2, b2, E2);
    latents_kernel<<<N_ / 256, 256, 0, stream>>>(E1, E2, eps, y, a,
        Wc1, bc1, Wc2, bc2, zx1, zs1, zx2, zs2, st);
    dec_bce_kernel<<<N_ / DB_ROWS, 256, 0, stream>>>(zx1, zs1, zx2, zs2, x, a,
        Wd1, bd1, Wd2, bd2, st);
    finalize_out_kernel<<<1, 64, 0, stream>>>(st, (float*)d_out);
}